// Round 1
// baseline (880.158 us; speedup 1.0000x reference)
//
#include <hip/hip_runtime.h>
#include <hip/hip_bf16.h>
#include <math.h>

// Problem constants
#define Bsz 64
#define Nn 512
#define Ff 128
#define Hh 256
#define OUTD 6
#define MTOT (Bsz * Nn)   // 32768

// ---------------- Generic tiled fp32 GEMM ----------------
// C[M,N] = (flags&1 ? C : 0) + A[M,K] @ B[K,N] + bias; flags&2 -> relu
// Batched via blockIdx.z with element strides (0 strides = shared operand).
#define BM 64
#define BN 64
#define BKk 16

__global__ __launch_bounds__(256) void gemm_tile(
    const float* __restrict__ A, const float* __restrict__ B,
    const float* __restrict__ bias, float* __restrict__ C,
    int M, int N, int K,
    long strideA, long strideB, long strideC,
    int flags)
{
    int b = blockIdx.z;
    A += (long)b * strideA;
    B += (long)b * strideB;
    C += (long)b * strideC;

    __shared__ __align__(16) float As[BKk][BM + 4];  // [k][m], row stride 68 floats (16B aligned)
    __shared__ __align__(16) float Bs[BKk][BN];      // [k][n]

    int tid = threadIdx.x;
    int tx = tid & 15, ty = tid >> 4;
    int row0 = blockIdx.x * BM, col0 = blockIdx.y * BN;

    float acc[4][4] = {};

    for (int k0 = 0; k0 < K; k0 += BKk) {
        #pragma unroll
        for (int l = 0; l < 4; ++l) {
            int t = tid + l * 256;          // 0..1023
            int m = t >> 4, k = t & 15;     // A tile 64x16
            As[k][m] = A[(long)(row0 + m) * K + (k0 + k)];
        }
        #pragma unroll
        for (int l = 0; l < 4; ++l) {
            int t = tid + l * 256;
            int k = t >> 6, n = t & 63;     // B tile 16x64
            Bs[k][n] = B[(long)(k0 + k) * N + (col0 + n)];
        }
        __syncthreads();
        #pragma unroll
        for (int k = 0; k < BKk; ++k) {
            float4 av4 = *(const float4*)&As[k][ty * 4];
            float4 bv4 = *(const float4*)&Bs[k][tx * 4];
            float av[4] = {av4.x, av4.y, av4.z, av4.w};
            float bv[4] = {bv4.x, bv4.y, bv4.z, bv4.w};
            #pragma unroll
            for (int i = 0; i < 4; ++i)
                #pragma unroll
                for (int j = 0; j < 4; ++j)
                    acc[i][j] += av[i] * bv[j];
        }
        __syncthreads();
    }

    #pragma unroll
    for (int i = 0; i < 4; ++i) {
        int r = row0 + ty * 4 + i;
        #pragma unroll
        for (int j = 0; j < 4; ++j) {
            int c = col0 + tx * 4 + j;
            float v = acc[i][j];
            if (bias) v += bias[c];
            long idx = (long)r * N + c;
            if (flags & 1) v += C[idx];
            if (flags & 2) v = fmaxf(v, 0.f);
            C[idx] = v;
        }
    }
}

// ---------------- per-row sum of squares of h0 ----------------
__global__ __launch_bounds__(64) void rowsq_kernel(const float* __restrict__ h0,
                                                   float* __restrict__ sq)
{
    int row = blockIdx.x;
    const float* r = h0 + (long)row * Ff;
    int lane = threadIdx.x;
    float a = r[lane], b = r[lane + 64];
    float v = a * a + b * b;
    #pragma unroll
    for (int off = 32; off; off >>= 1) v += __shfl_down(v, off);
    if (lane == 0) sq[row] = v;
}

// ---------------- Gram -> Gaussian adjacency A ----------------
// A[b,i,j] = (i==j) ? 0 : exp(-max(sq_i+sq_j-2*dot(h_i,h_j),0) / (2*sigma^2))
__global__ __launch_bounds__(256) void gram_A_kernel(
    const float* __restrict__ h0, const float* __restrict__ sq,
    const float* __restrict__ sigma, float* __restrict__ Aout)
{
    int b = blockIdx.z;
    const float* H = h0 + (long)b * Nn * Ff;
    const float* SQ = sq + b * Nn;
    float* Ab = Aout + (long)b * Nn * Nn;

    __shared__ __align__(16) float Is[16][64 + 4];
    __shared__ __align__(16) float Js[16][64 + 4];

    int tid = threadIdx.x;
    int tx = tid & 15, ty = tid >> 4;
    int i0 = blockIdx.x * 64, j0 = blockIdx.y * 64;

    float acc[4][4] = {};

    for (int k0 = 0; k0 < Ff; k0 += 16) {
        #pragma unroll
        for (int l = 0; l < 4; ++l) {
            int t = tid + l * 256;
            int m = t >> 4, k = t & 15;
            Is[k][m] = H[(i0 + m) * Ff + (k0 + k)];
            Js[k][m] = H[(j0 + m) * Ff + (k0 + k)];
        }
        __syncthreads();
        #pragma unroll
        for (int k = 0; k < 16; ++k) {
            float4 av4 = *(const float4*)&Is[k][ty * 4];
            float4 bv4 = *(const float4*)&Js[k][tx * 4];
            float av[4] = {av4.x, av4.y, av4.z, av4.w};
            float bv[4] = {bv4.x, bv4.y, bv4.z, bv4.w};
            #pragma unroll
            for (int i = 0; i < 4; ++i)
                #pragma unroll
                for (int j = 0; j < 4; ++j)
                    acc[i][j] += av[i] * bv[j];
        }
        __syncthreads();
    }

    float s = sigma[0];
    float inv2s2 = 1.0f / (2.0f * s * s);
    #pragma unroll
    for (int i = 0; i < 4; ++i) {
        int r = i0 + ty * 4 + i;
        float sqr = SQ[r];
        #pragma unroll
        for (int j = 0; j < 4; ++j) {
            int c = j0 + tx * 4 + j;
            float d = sqr + SQ[c] - 2.0f * acc[i][j];
            d = fmaxf(d, 0.0f);
            float a = (r == c) ? 0.0f : expf(-d * inv2s2);
            Ab[r * Nn + c] = a;
        }
    }
}

// ---------------- mean pool over N ----------------
__global__ __launch_bounds__(256) void pool_mean_kernel(const float* __restrict__ h3,
                                                        float* __restrict__ g)
{
    int b = blockIdx.x;
    int f = threadIdx.x;  // 256
    const float* p = h3 + (long)b * Nn * Hh + f;
    float s = 0.f;
    for (int n = 0; n < Nn; ++n) s += p[n * Hh];
    g[b * Hh + f] = s * (1.0f / (float)Nn);
}

// ---------------- g2 = relu(g @ W1 + b1) ----------------
__global__ __launch_bounds__(256) void mlp1_kernel(const float* __restrict__ g,
                                                   const float* __restrict__ W1,
                                                   const float* __restrict__ b1,
                                                   float* __restrict__ g2)
{
    int b = blockIdx.x;
    int j = threadIdx.x;  // 256
    __shared__ float gs[Hh];
    gs[j] = g[b * Hh + j];
    __syncthreads();
    float s = b1[j];
    for (int k = 0; k < Hh; ++k) s += gs[k] * W1[k * Hh + j];
    g2[b * Hh + j] = fmaxf(s, 0.f);
}

// ---------------- out = g2 @ Wout + bout ----------------
__global__ __launch_bounds__(64) void mlp_out_kernel(const float* __restrict__ g2,
                                                     const float* __restrict__ Wout,
                                                     const float* __restrict__ bout,
                                                     float* __restrict__ out)
{
    int b = blockIdx.x;
    int j = threadIdx.x;  // 64
    __shared__ float gs[Hh];
    for (int t = j; t < Hh; t += 64) gs[t] = g2[b * Hh + t];
    __syncthreads();
    if (j < OUTD) {
        float s = bout[j];
        for (int k = 0; k < Hh; ++k) s += gs[k] * Wout[k * OUTD + j];
        out[b * OUTD + j] = s;
    }
}

extern "C" void kernel_launch(void* const* d_in, const int* in_sizes, int n_in,
                              void* d_out, int out_size, void* d_ws, size_t ws_size,
                              hipStream_t stream) {
    const float* x      = (const float*)d_in[0];
    // d_in[1] edge_index, d_in[2] edge_weight, d_in[3] batch: unused (recomputed internally)
    const float* sigma  = (const float*)d_in[4];
    const float* Wg     = (const float*)d_in[5];
    const float* bg     = (const float*)d_in[6];
    const float* Wrel0  = (const float*)d_in[7];
    const float* Wroot0 = (const float*)d_in[8];
    const float* brel0  = (const float*)d_in[9];
    const float* Wrel1  = (const float*)d_in[10];
    const float* Wroot1 = (const float*)d_in[11];
    const float* brel1  = (const float*)d_in[12];
    const float* Wrel2  = (const float*)d_in[13];
    const float* Wroot2 = (const float*)d_in[14];
    const float* brel2  = (const float*)d_in[15];
    const float* W1     = (const float*)d_in[16];
    const float* b1     = (const float*)d_in[17];
    const float* Wout   = (const float*)d_in[18];
    const float* bout   = (const float*)d_in[19];
    float* out = (float*)d_out;

    // Workspace layout (fp32 elements)
    char* ws = (char*)d_ws;
    float* h0  = (float*)(ws);                                   // 32768*128 = 16 MB
    float* sq  = (float*)(ws + (size_t)16777216);                // 128 KB
    float* A   = (float*)(ws + (size_t)16908288);                // 64*512*512*4 = 64 MB
    float* agg = (float*)(ws + (size_t)84017152);                // 32 MB
    float* hA  = (float*)(ws + (size_t)117571584);               // 32 MB (h1 / h3)
    float* hB  = (float*)(ws + (size_t)151126016);               // 32 MB (h2)
    float* g   = (float*)(ws + (size_t)184680448);               // 64 KB
    float* g2  = (float*)(ws + (size_t)184745984);               // 64 KB

    // h0 = x @ Wg + bg              [32768,128]
    gemm_tile<<<dim3(MTOT / BM, Ff / BN, 1), 256, 0, stream>>>(
        x, Wg, bg, h0, MTOT, Ff, Ff, 0, 0, 0, 0);

    // sq[i] = ||h0_i||^2
    rowsq_kernel<<<MTOT, 64, 0, stream>>>(h0, sq);

    // A[b] = exp(-dist/(2 sigma^2)), zero diagonal      [64,512,512]
    gram_A_kernel<<<dim3(Nn / 64, Nn / 64, Bsz), 256, 0, stream>>>(h0, sq, sigma, A);

    // ---- layer 0 ----  (A symmetric => einsum('bji,bjf') == A @ h)
    gemm_tile<<<dim3(Nn / BM, Ff / BN, Bsz), 256, 0, stream>>>(
        A, h0, nullptr, agg, Nn, Ff, Nn,
        (long)Nn * Nn, (long)Nn * Ff, (long)Nn * Ff, 0);
    gemm_tile<<<dim3(MTOT / BM, Hh / BN, 1), 256, 0, stream>>>(
        agg, Wrel0, brel0, hA, MTOT, Hh, Ff, 0, 0, 0, 0);
    gemm_tile<<<dim3(MTOT / BM, Hh / BN, 1), 256, 0, stream>>>(
        h0, Wroot0, nullptr, hA, MTOT, Hh, Ff, 0, 0, 0, 1 | 2);   // acc + relu

    // ---- layer 1 ----
    gemm_tile<<<dim3(Nn / BM, Hh / BN, Bsz), 256, 0, stream>>>(
        A, hA, nullptr, agg, Nn, Hh, Nn,
        (long)Nn * Nn, (long)Nn * Hh, (long)Nn * Hh, 0);
    gemm_tile<<<dim3(MTOT / BM, Hh / BN, 1), 256, 0, stream>>>(
        agg, Wrel1, brel1, hB, MTOT, Hh, Hh, 0, 0, 0, 0);
    gemm_tile<<<dim3(MTOT / BM, Hh / BN, 1), 256, 0, stream>>>(
        hA, Wroot1, nullptr, hB, MTOT, Hh, Hh, 0, 0, 0, 1 | 2);   // acc + relu

    // ---- layer 2 (no relu) ----
    gemm_tile<<<dim3(Nn / BM, Hh / BN, Bsz), 256, 0, stream>>>(
        A, hB, nullptr, agg, Nn, Hh, Nn,
        (long)Nn * Nn, (long)Nn * Hh, (long)Nn * Hh, 0);
    gemm_tile<<<dim3(MTOT / BM, Hh / BN, 1), 256, 0, stream>>>(
        agg, Wrel2, brel2, hA, MTOT, Hh, Hh, 0, 0, 0, 0);
    gemm_tile<<<dim3(MTOT / BM, Hh / BN, 1), 256, 0, stream>>>(
        hB, Wroot2, nullptr, hA, MTOT, Hh, Hh, 0, 0, 0, 1);       // acc, no relu

    // pool + MLP head
    pool_mean_kernel<<<Bsz, 256, 0, stream>>>(hA, g);
    mlp1_kernel<<<Bsz, 256, 0, stream>>>(g, W1, b1, g2);
    mlp_out_kernel<<<Bsz, 64, 0, stream>>>(g2, Wout, bout, out);
}

// Round 2
// 363.681 us; speedup vs baseline: 2.4201x; 2.4201x over previous
//
#include <hip/hip_runtime.h>
#include <math.h>

// Problem constants
#define Bsz 64
#define Nn 512
#define Ff 128
#define Hh 256
#define OUTD 6
#define MTOT (Bsz * Nn)   // 32768

typedef __bf16 bf16x8 __attribute__((ext_vector_type(8)));
typedef float f32x4 __attribute__((ext_vector_type(4)));
typedef int int4v __attribute__((ext_vector_type(4)));
typedef unsigned short ushort4v __attribute__((ext_vector_type(4)));

__device__ __forceinline__ unsigned short f2bf(float f) {
    unsigned u = __float_as_uint(f);
    u += 0x7FFFu + ((u >> 16) & 1u);        // RNE
    return (unsigned short)(u >> 16);
}
__device__ __forceinline__ float bf2f(unsigned short s) {
    return __uint_as_float(((unsigned)s) << 16);
}

// ---------------- fp32 tiled GEMM (h0 = x@Wg + bg only) ----------------
#define BM 64
#define BN 64
#define BKk 16

__global__ __launch_bounds__(256) void gemm_tile(
    const float* __restrict__ A, const float* __restrict__ B,
    const float* __restrict__ bias, float* __restrict__ C,
    int M, int N, int K)
{
    __shared__ __align__(16) float As[BKk][BM + 4];
    __shared__ __align__(16) float Bs[BKk][BN];

    int tid = threadIdx.x;
    int tx = tid & 15, ty = tid >> 4;
    int row0 = blockIdx.x * BM, col0 = blockIdx.y * BN;

    float acc[4][4] = {};

    for (int k0 = 0; k0 < K; k0 += BKk) {
        #pragma unroll
        for (int l = 0; l < 4; ++l) {
            int t = tid + l * 256;
            int m = t >> 4, k = t & 15;
            As[k][m] = A[(long)(row0 + m) * K + (k0 + k)];
        }
        #pragma unroll
        for (int l = 0; l < 4; ++l) {
            int t = tid + l * 256;
            int k = t >> 6, n = t & 63;
            Bs[k][n] = B[(long)(k0 + k) * N + (col0 + n)];
        }
        __syncthreads();
        #pragma unroll
        for (int k = 0; k < BKk; ++k) {
            float4 av4 = *(const float4*)&As[k][ty * 4];
            float4 bv4 = *(const float4*)&Bs[k][tx * 4];
            float av[4] = {av4.x, av4.y, av4.z, av4.w};
            float bv[4] = {bv4.x, bv4.y, bv4.z, bv4.w};
            #pragma unroll
            for (int i = 0; i < 4; ++i)
                #pragma unroll
                for (int j = 0; j < 4; ++j)
                    acc[i][j] += av[i] * bv[j];
        }
        __syncthreads();
    }

    #pragma unroll
    for (int i = 0; i < 4; ++i) {
        int r = row0 + ty * 4 + i;
        #pragma unroll
        for (int j = 0; j < 4; ++j) {
            int c = col0 + tx * 4 + j;
            C[(long)r * N + c] = acc[i][j] + bias[c];
        }
    }
}

// ---------------- bf16 MFMA GEMM, optional fused second operand pair ----------------
// out = act( A0@B0 [+ A1@B1] + bias ), bf16 out; B given TRANSPOSED (BT[n][k]).
// Batched via blockIdx.z strides. flags&1 = relu. CT (optional) = transposed copy
// of out laid out [graph][n][node] (node = row & 511).
#define LDH 40   // LDS row stride in bf16 elems: 80 B (16B-aligned, 2-way bank alias = free)

__global__ __launch_bounds__(256) void gemm_bf16(
    const unsigned short* __restrict__ A0, const unsigned short* __restrict__ B0T,
    const unsigned short* __restrict__ A1, const unsigned short* __restrict__ B1T,
    const float* __restrict__ bias,
    unsigned short* __restrict__ C, unsigned short* __restrict__ CT,
    int M, int Ntot, int K0, int K1, int lda0, int lda1,
    long strideA0, long strideB0, long strideC, int flags)
{
    int bz = blockIdx.z;
    A0 += (long)bz * strideA0;
    B0T += (long)bz * strideB0;
    C += (long)bz * strideC;

    __shared__ unsigned short As[128 * LDH];
    __shared__ unsigned short Bs[128 * LDH];

    int tid = threadIdx.x;
    int lane = tid & 63;
    int wave = tid >> 6;
    int quad = lane >> 4, l16 = lane & 15;
    int wm = (wave >> 1) * 64, wn = (wave & 1) * 64;
    int m0 = blockIdx.x * 128, n0 = blockIdx.y * 128;

    f32x4 acc[4][4] = {};

    #pragma unroll
    for (int pass = 0; pass < 2; ++pass) {
        const unsigned short* Ap = pass ? A1 : A0;
        const unsigned short* Bp = pass ? B1T : B0T;
        int K = pass ? K1 : K0;
        int lda = pass ? lda1 : lda0;
        if (K == 0) continue;
        for (int k0 = 0; k0 < K; k0 += 32) {
            __syncthreads();   // guard LDS against previous iteration's readers
            #pragma unroll
            for (int l = 0; l < 2; ++l) {
                int idx = tid + l * 256;      // 0..511
                int r = idx >> 2, ch = idx & 3;
                int4v va = *(const int4v*)(Ap + (long)(m0 + r) * lda + k0 + ch * 8);
                *(int4v*)&As[r * LDH + ch * 8] = va;
                int4v vb = *(const int4v*)(Bp + (long)(n0 + r) * K + k0 + ch * 8);
                *(int4v*)&Bs[r * LDH + ch * 8] = vb;
            }
            __syncthreads();
            bf16x8 af[4], bfr[4];
            #pragma unroll
            for (int i = 0; i < 4; ++i)
                af[i] = *(const bf16x8*)&As[(wm + i * 16 + l16) * LDH + quad * 8];
            #pragma unroll
            for (int j = 0; j < 4; ++j)
                bfr[j] = *(const bf16x8*)&Bs[(wn + j * 16 + l16) * LDH + quad * 8];
            #pragma unroll
            for (int i = 0; i < 4; ++i)
                #pragma unroll
                for (int j = 0; j < 4; ++j)
                    acc[i][j] = __builtin_amdgcn_mfma_f32_16x16x32_bf16(
                        af[i], bfr[j], acc[i][j], 0, 0, 0);
        }
    }

    // Epilogue. C/D layout: col = lane&15, row = quad*4 + reg  (4 consecutive rows/lane)
    int ldc = Ntot;
    #pragma unroll
    for (int i = 0; i < 4; ++i) {
        int mb = m0 + wm + i * 16 + quad * 4;
        #pragma unroll
        for (int j = 0; j < 4; ++j) {
            int n = n0 + wn + j * 16 + l16;
            f32x4 v = acc[i][j];
            float bv = bias ? bias[n] : 0.0f;
            float o0 = v[0] + bv, o1 = v[1] + bv, o2 = v[2] + bv, o3 = v[3] + bv;
            if (flags & 1) {
                o0 = fmaxf(o0, 0.f); o1 = fmaxf(o1, 0.f);
                o2 = fmaxf(o2, 0.f); o3 = fmaxf(o3, 0.f);
            }
            unsigned short s0 = f2bf(o0), s1 = f2bf(o1), s2 = f2bf(o2), s3 = f2bf(o3);
            C[(long)(mb + 0) * ldc + n] = s0;
            C[(long)(mb + 1) * ldc + n] = s1;
            C[(long)(mb + 2) * ldc + n] = s2;
            C[(long)(mb + 3) * ldc + n] = s3;
            if (CT) {
                ushort4v p; p[0] = s0; p[1] = s1; p[2] = s2; p[3] = s3;
                long ti = ((long)(mb >> 9) * Ntot + n) * 512 + (mb & 511);
                *(ushort4v*)&CT[ti] = p;   // 4 consecutive nodes -> 8B packed store
            }
        }
    }
}

// ---------------- weight convert + transpose (fp32 [in][256] -> bf16 [256][in]) ----
__global__ __launch_bounds__(256) void convert_weights(
    const float* __restrict__ Wrel0, const float* __restrict__ Wroot0,
    const float* __restrict__ Wrel1, const float* __restrict__ Wroot1,
    const float* __restrict__ Wrel2, const float* __restrict__ Wroot2,
    unsigned short* __restrict__ T0, unsigned short* __restrict__ T1,
    unsigned short* __restrict__ T2, unsigned short* __restrict__ T3,
    unsigned short* __restrict__ T4, unsigned short* __restrict__ T5)
{
    int idx = blockIdx.x * 256 + threadIdx.x;   // total 327680
    const float* src; unsigned short* dst; int kin; int e;
    if      (idx <  32768) { src = Wrel0;  dst = T0; kin = 128; e = idx; }
    else if (idx <  65536) { src = Wroot0; dst = T1; kin = 128; e = idx - 32768; }
    else if (idx < 131072) { src = Wrel1;  dst = T2; kin = 256; e = idx - 65536; }
    else if (idx < 196608) { src = Wroot1; dst = T3; kin = 256; e = idx - 131072; }
    else if (idx < 262144) { src = Wrel2;  dst = T4; kin = 256; e = idx - 196608; }
    else                   { src = Wroot2; dst = T5; kin = 256; e = idx - 262144; }
    int o = (kin == 128) ? (e >> 7) : (e >> 8);
    int i = e & (kin - 1);
    dst[e] = f2bf(src[(long)i * 256 + o]);      // all out-dims are 256
}

// ---------------- h0 fp32 -> bf16 node-major + bf16 transposed ----------------
__global__ __launch_bounds__(256) void convert_h0(
    const float* __restrict__ h0, unsigned short* __restrict__ h0b,
    unsigned short* __restrict__ h0T)
{
    __shared__ unsigned short T[128][72];   // stride 144 B (16B-aligned)
    int m0 = blockIdx.x * 64;               // 64 nodes per block
    int tid = threadIdx.x;
    #pragma unroll
    for (int l = 0; l < 32; ++l) {
        int idx = tid + l * 256;            // 0..8191
        int r = idx >> 7, c = idx & 127;
        float v = h0[(long)(m0 + r) * 128 + c];
        unsigned short s = f2bf(v);
        h0b[(long)(m0 + r) * 128 + c] = s;
        T[c][r] = s;
    }
    __syncthreads();
    int b = m0 >> 9, nn0 = m0 & 511;
    #pragma unroll
    for (int l = 0; l < 2; ++l) {
        int idx = tid + l * 256;            // f = idx>>2 (128 rows), ch = idx&3
        int f = idx >> 2, ch = idx & 3;
        int4v v0 = *(const int4v*)&T[f][ch * 16];
        int4v v1 = *(const int4v*)&T[f][ch * 16 + 8];
        unsigned short* dst = &h0T[((long)b * 128 + f) * 512 + nn0 + ch * 16];
        *(int4v*)dst = v0;
        *(int4v*)(dst + 8) = v1;
    }
}

// ---------------- per-row sum of squares of h0 (fp32) ----------------
__global__ __launch_bounds__(64) void rowsq_kernel(const float* __restrict__ h0,
                                                   float* __restrict__ sq)
{
    int row = blockIdx.x;
    const float* r = h0 + (long)row * Ff;
    int lane = threadIdx.x;
    float a = r[lane], b = r[lane + 64];
    float v = a * a + b * b;
    #pragma unroll
    for (int off = 32; off; off >>= 1) v += __shfl_down(v, off);
    if (lane == 0) sq[row] = v;
}

// ---------------- Gram -> Gaussian adjacency A (fp32 math, bf16 store) ----------
__global__ __launch_bounds__(256) void gram_A_kernel(
    const float* __restrict__ h0, const float* __restrict__ sq,
    const float* __restrict__ sigma, unsigned short* __restrict__ Aout)
{
    int b = blockIdx.z;
    const float* H = h0 + (long)b * Nn * Ff;
    const float* SQ = sq + b * Nn;
    unsigned short* Ab = Aout + (long)b * Nn * Nn;

    __shared__ __align__(16) float Is[16][64 + 4];
    __shared__ __align__(16) float Js[16][64 + 4];

    int tid = threadIdx.x;
    int tx = tid & 15, ty = tid >> 4;
    int i0 = blockIdx.x * 64, j0 = blockIdx.y * 64;

    float acc[4][4] = {};

    for (int k0 = 0; k0 < Ff; k0 += 16) {
        #pragma unroll
        for (int l = 0; l < 4; ++l) {
            int t = tid + l * 256;
            int m = t >> 4, k = t & 15;
            Is[k][m] = H[(i0 + m) * Ff + (k0 + k)];
            Js[k][m] = H[(j0 + m) * Ff + (k0 + k)];
        }
        __syncthreads();
        #pragma unroll
        for (int k = 0; k < 16; ++k) {
            float4 av4 = *(const float4*)&Is[k][ty * 4];
            float4 bv4 = *(const float4*)&Js[k][tx * 4];
            float av[4] = {av4.x, av4.y, av4.z, av4.w};
            float bv[4] = {bv4.x, bv4.y, bv4.z, bv4.w};
            #pragma unroll
            for (int i = 0; i < 4; ++i)
                #pragma unroll
                for (int j = 0; j < 4; ++j)
                    acc[i][j] += av[i] * bv[j];
        }
        __syncthreads();
    }

    float s = sigma[0];
    float inv2s2 = 1.0f / (2.0f * s * s);
    #pragma unroll
    for (int i = 0; i < 4; ++i) {
        int r = i0 + ty * 4 + i;
        float sqr = SQ[r];
        ushort4v pk;
        #pragma unroll
        for (int j = 0; j < 4; ++j) {
            int c = j0 + tx * 4 + j;
            float d = fmaxf(sqr + SQ[c] - 2.0f * acc[i][j], 0.0f);
            float a = (r == c) ? 0.0f : __expf(-d * inv2s2);
            pk[j] = f2bf(a);
        }
        *(ushort4v*)&Ab[(long)r * Nn + j0 + tx * 4] = pk;
    }
}

// ---------------- mean pool over N (bf16 in, fp32 out) ----------------
__global__ __launch_bounds__(256) void pool_mean_kernel(const unsigned short* __restrict__ h3,
                                                        float* __restrict__ g)
{
    int b = blockIdx.x;
    int f = threadIdx.x;  // 256
    const unsigned short* p = h3 + (long)b * Nn * Hh + f;
    float s = 0.f;
    for (int n = 0; n < Nn; ++n) s += bf2f(p[n * Hh]);
    g[b * Hh + f] = s * (1.0f / (float)Nn);
}

// ---------------- g2 = relu(g @ W1 + b1) (fp32) ----------------
__global__ __launch_bounds__(256) void mlp1_kernel(const float* __restrict__ g,
                                                   const float* __restrict__ W1,
                                                   const float* __restrict__ b1,
                                                   float* __restrict__ g2)
{
    int b = blockIdx.x;
    int j = threadIdx.x;
    __shared__ float gs[Hh];
    gs[j] = g[b * Hh + j];
    __syncthreads();
    float s = b1[j];
    for (int k = 0; k < Hh; ++k) s += gs[k] * W1[k * Hh + j];
    g2[b * Hh + j] = fmaxf(s, 0.f);
}

// ---------------- out = g2 @ Wout + bout (fp32) ----------------
__global__ __launch_bounds__(64) void mlp_out_kernel(const float* __restrict__ g2,
                                                     const float* __restrict__ Wout,
                                                     const float* __restrict__ bout,
                                                     float* __restrict__ out)
{
    int b = blockIdx.x;
    int j = threadIdx.x;
    __shared__ float gs[Hh];
    for (int t = j; t < Hh; t += 64) gs[t] = g2[b * Hh + t];
    __syncthreads();
    if (j < OUTD) {
        float s = bout[j];
        for (int k = 0; k < Hh; ++k) s += gs[k] * Wout[k * OUTD + j];
        out[b * OUTD + j] = s;
    }
}

extern "C" void kernel_launch(void* const* d_in, const int* in_sizes, int n_in,
                              void* d_out, int out_size, void* d_ws, size_t ws_size,
                              hipStream_t stream) {
    const float* x      = (const float*)d_in[0];
    const float* sigma  = (const float*)d_in[4];
    const float* Wg     = (const float*)d_in[5];
    const float* bg     = (const float*)d_in[6];
    const float* Wrel0  = (const float*)d_in[7];
    const float* Wroot0 = (const float*)d_in[8];
    const float* brel0  = (const float*)d_in[9];
    const float* Wrel1  = (const float*)d_in[10];
    const float* Wroot1 = (const float*)d_in[11];
    const float* brel1  = (const float*)d_in[12];
    const float* Wrel2  = (const float*)d_in[13];
    const float* Wroot2 = (const float*)d_in[14];
    const float* brel2  = (const float*)d_in[15];
    const float* W1     = (const float*)d_in[16];
    const float* b1     = (const float*)d_in[17];
    const float* Wout   = (const float*)d_in[18];
    const float* bout   = (const float*)d_in[19];
    float* out = (float*)d_out;

    // Workspace layout (bytes)
    char* ws = (char*)d_ws;
    float*          h0f  = (float*)(ws + 0);                       // 16 MB fp32
    unsigned short* h0b  = (unsigned short*)(ws + 16777216);       // 8 MB
    unsigned short* h0T  = (unsigned short*)(ws + 25165824);       // 8 MB
    float*          sq   = (float*)(ws + 33554432);                // 128 KB
    unsigned short* Aadj = (unsigned short*)(ws + 33685504);       // 32 MB
    unsigned short* agg  = (unsigned short*)(ws + 67239936);       // 16 MB
    unsigned short* h1b  = (unsigned short*)(ws + 84017152);       // 16 MB
    unsigned short* h1T  = (unsigned short*)(ws + 100794368);      // 16 MB
    unsigned short* h2b  = (unsigned short*)(ws + 117571584);      // 16 MB
    unsigned short* h2T  = (unsigned short*)(ws + 134348800);      // 16 MB
    unsigned short* h3b  = (unsigned short*)(ws + 151126016);      // 16 MB
    unsigned short* WrelT0  = (unsigned short*)(ws + 167903232);   // 64 KB
    unsigned short* WrootT0 = (unsigned short*)(ws + 167968768);   // 64 KB
    unsigned short* WrelT1  = (unsigned short*)(ws + 168034304);   // 128 KB
    unsigned short* WrootT1 = (unsigned short*)(ws + 168165376);   // 128 KB
    unsigned short* WrelT2  = (unsigned short*)(ws + 168296448);   // 128 KB
    unsigned short* WrootT2 = (unsigned short*)(ws + 168427520);   // 128 KB
    float*          g    = (float*)(ws + 168558592);               // 64 KB
    float*          g2   = (float*)(ws + 168624128);               // 64 KB

    // weights -> bf16 transposed
    convert_weights<<<1280, 256, 0, stream>>>(Wrel0, Wroot0, Wrel1, Wroot1, Wrel2, Wroot2,
                                              WrelT0, WrootT0, WrelT1, WrootT1, WrelT2, WrootT2);

    // h0 = x @ Wg + bg (fp32; feeds the exp path)
    gemm_tile<<<dim3(MTOT / BM, Ff / BN, 1), 256, 0, stream>>>(x, Wg, bg, h0f, MTOT, Ff, Ff);

    // h0 -> bf16 (node-major + transposed)
    convert_h0<<<MTOT / 64, 256, 0, stream>>>(h0f, h0b, h0T);

    // sq, then A (fp32 math, bf16 store)
    rowsq_kernel<<<MTOT, 64, 0, stream>>>(h0f, sq);
    gram_A_kernel<<<dim3(Nn / 64, Nn / 64, Bsz), 256, 0, stream>>>(h0f, sq, sigma, Aadj);

    // ---- layer 0 ----
    gemm_bf16<<<dim3(4, 1, Bsz), 256, 0, stream>>>(
        Aadj, h0T, nullptr, nullptr, nullptr, agg, nullptr,
        Nn, Ff, Nn, 0, Nn, 0,
        (long)Nn * Nn, (long)Ff * Nn, (long)Nn * Ff, 0);
    gemm_bf16<<<dim3(MTOT / 128, Hh / 128, 1), 256, 0, stream>>>(
        agg, WrelT0, h0b, WrootT0, brel0, h1b, h1T,
        MTOT, Hh, Ff, Ff, Ff, Ff, 0, 0, 0, 1);

    // ---- layer 1 ----
    gemm_bf16<<<dim3(4, 2, Bsz), 256, 0, stream>>>(
        Aadj, h1T, nullptr, nullptr, nullptr, agg, nullptr,
        Nn, Hh, Nn, 0, Nn, 0,
        (long)Nn * Nn, (long)Hh * Nn, (long)Nn * Hh, 0);
    gemm_bf16<<<dim3(MTOT / 128, Hh / 128, 1), 256, 0, stream>>>(
        agg, WrelT1, h1b, WrootT1, brel1, h2b, h2T,
        MTOT, Hh, Hh, Hh, Hh, Hh, 0, 0, 0, 1);

    // ---- layer 2 (no relu, no transpose needed) ----
    gemm_bf16<<<dim3(4, 2, Bsz), 256, 0, stream>>>(
        Aadj, h2T, nullptr, nullptr, nullptr, agg, nullptr,
        Nn, Hh, Nn, 0, Nn, 0,
        (long)Nn * Nn, (long)Hh * Nn, (long)Nn * Hh, 0);
    gemm_bf16<<<dim3(MTOT / 128, Hh / 128, 1), 256, 0, stream>>>(
        agg, WrelT2, h2b, WrootT2, brel2, h3b, nullptr,
        MTOT, Hh, Hh, Hh, Hh, Hh, 0, 0, 0, 0);

    // pool + MLP head (fp32)
    pool_mean_kernel<<<Bsz, 256, 0, stream>>>(h3b, g);
    mlp1_kernel<<<Bsz, 256, 0, stream>>>(g, W1, b1, g2);
    mlp_out_kernel<<<Bsz, 64, 0, stream>>>(g2, Wout, bout, out);
}

// Round 3
// 306.687 us; speedup vs baseline: 2.8699x; 1.1858x over previous
//
#include <hip/hip_runtime.h>
#include <math.h>

// Problem constants
#define Bsz 64
#define Nn 512
#define Ff 128
#define Hh 256
#define OUTD 6
#define MTOT (Bsz * Nn)   // 32768

typedef __bf16 bf16x8 __attribute__((ext_vector_type(8)));
typedef float f32x4 __attribute__((ext_vector_type(4)));
typedef int int4v __attribute__((ext_vector_type(4)));
typedef unsigned short ushort4v __attribute__((ext_vector_type(4)));

__device__ __forceinline__ unsigned short f2bf(float f) {
    unsigned u = __float_as_uint(f);
    u += 0x7FFFu + ((u >> 16) & 1u);        // RNE
    return (unsigned short)(u >> 16);
}
__device__ __forceinline__ float bf2f(unsigned short s) {
    return __uint_as_float(((unsigned)s) << 16);
}

#define LDH 40   // LDS row stride in bf16 elems (80 B, 16B-aligned)

// ---------------- bf16 MFMA GEMM, optional fused second operand pair ----------------
// out = act( A0@B0 [+ A1@B1] + bias ), bf16 out; B given TRANSPOSED (BT[n][k]).
// Batched via blockIdx.z strides. flags&1 = relu. CT (optional) = transposed copy
// of out laid out [graph][n][node] (node = row & 511).
__global__ __launch_bounds__(256) void gemm_bf16(
    const unsigned short* __restrict__ A0, const unsigned short* __restrict__ B0T,
    const unsigned short* __restrict__ A1, const unsigned short* __restrict__ B1T,
    const float* __restrict__ bias,
    unsigned short* __restrict__ C, unsigned short* __restrict__ CT,
    int M, int Ntot, int K0, int K1, int lda0, int lda1,
    long strideA0, long strideB0, long strideC, int flags)
{
    int bz = blockIdx.z;
    A0 += (long)bz * strideA0;
    B0T += (long)bz * strideB0;
    C += (long)bz * strideC;

    __shared__ unsigned short As[128 * LDH];
    __shared__ unsigned short Bs[128 * LDH];

    int tid = threadIdx.x;
    int lane = tid & 63;
    int wave = tid >> 6;
    int quad = lane >> 4, l16 = lane & 15;
    int wm = (wave >> 1) * 64, wn = (wave & 1) * 64;
    int m0 = blockIdx.x * 128, n0 = blockIdx.y * 128;

    f32x4 acc[4][4] = {};

    #pragma unroll
    for (int pass = 0; pass < 2; ++pass) {
        const unsigned short* Ap = pass ? A1 : A0;
        const unsigned short* Bp = pass ? B1T : B0T;
        int K = pass ? K1 : K0;
        int lda = pass ? lda1 : lda0;
        if (K == 0) continue;
        for (int k0 = 0; k0 < K; k0 += 32) {
            __syncthreads();
            #pragma unroll
            for (int l = 0; l < 2; ++l) {
                int idx = tid + l * 256;      // 0..511
                int r = idx >> 2, ch = idx & 3;
                int4v va = *(const int4v*)(Ap + (long)(m0 + r) * lda + k0 + ch * 8);
                *(int4v*)&As[r * LDH + ch * 8] = va;
                int4v vb = *(const int4v*)(Bp + (long)(n0 + r) * K + k0 + ch * 8);
                *(int4v*)&Bs[r * LDH + ch * 8] = vb;
            }
            __syncthreads();
            bf16x8 af[4], bfr[4];
            #pragma unroll
            for (int i = 0; i < 4; ++i)
                af[i] = *(const bf16x8*)&As[(wm + i * 16 + l16) * LDH + quad * 8];
            #pragma unroll
            for (int j = 0; j < 4; ++j)
                bfr[j] = *(const bf16x8*)&Bs[(wn + j * 16 + l16) * LDH + quad * 8];
            #pragma unroll
            for (int i = 0; i < 4; ++i)
                #pragma unroll
                for (int j = 0; j < 4; ++j)
                    acc[i][j] = __builtin_amdgcn_mfma_f32_16x16x32_bf16(
                        af[i], bfr[j], acc[i][j], 0, 0, 0);
        }
    }

    // Epilogue. C/D layout: col = lane&15, row = quad*4 + reg
    int ldc = Ntot;
    #pragma unroll
    for (int i = 0; i < 4; ++i) {
        int mb = m0 + wm + i * 16 + quad * 4;
        #pragma unroll
        for (int j = 0; j < 4; ++j) {
            int n = n0 + wn + j * 16 + l16;
            f32x4 v = acc[i][j];
            float bv = bias ? bias[n] : 0.0f;
            float o0 = v[0] + bv, o1 = v[1] + bv, o2 = v[2] + bv, o3 = v[3] + bv;
            if (flags & 1) {
                o0 = fmaxf(o0, 0.f); o1 = fmaxf(o1, 0.f);
                o2 = fmaxf(o2, 0.f); o3 = fmaxf(o3, 0.f);
            }
            unsigned short s0 = f2bf(o0), s1 = f2bf(o1), s2 = f2bf(o2), s3 = f2bf(o3);
            C[(long)(mb + 0) * ldc + n] = s0;
            C[(long)(mb + 1) * ldc + n] = s1;
            C[(long)(mb + 2) * ldc + n] = s2;
            C[(long)(mb + 3) * ldc + n] = s3;
            if (CT) {
                ushort4v p; p[0] = s0; p[1] = s1; p[2] = s2; p[3] = s3;
                long ti = ((long)(mb >> 9) * Ntot + n) * 512 + (mb & 511);
                *(ushort4v*)&CT[ti] = p;
            }
        }
    }
}

// ---------------- h0 = bf16(x) @ WgT + bg  (MFMA; writes h0b + h0T) ----------------
__global__ __launch_bounds__(256) void h0_mfma(
    const float* __restrict__ x, const unsigned short* __restrict__ WgT,
    const float* __restrict__ bg,
    unsigned short* __restrict__ h0b, unsigned short* __restrict__ h0T)
{
    __shared__ unsigned short As[128 * LDH];
    __shared__ unsigned short Bs[128 * LDH];

    int tid = threadIdx.x;
    int lane = tid & 63;
    int wave = tid >> 6;
    int quad = lane >> 4, l16 = lane & 15;
    int wm = (wave >> 1) * 64, wn = (wave & 1) * 64;
    int m0 = blockIdx.x * 128;          // N = 128 (single column block)

    f32x4 acc[4][4] = {};

    for (int k0 = 0; k0 < Ff; k0 += 32) {
        __syncthreads();
        #pragma unroll
        for (int l = 0; l < 2; ++l) {
            int idx = tid + l * 256;
            int r = idx >> 2, ch = idx & 3;
            const float* px = x + (long)(m0 + r) * Ff + k0 + ch * 8;
            float4 xa = *(const float4*)px;
            float4 xb = *(const float4*)(px + 4);
            ushort4v pa, pb;
            pa[0] = f2bf(xa.x); pa[1] = f2bf(xa.y); pa[2] = f2bf(xa.z); pa[3] = f2bf(xa.w);
            pb[0] = f2bf(xb.x); pb[1] = f2bf(xb.y); pb[2] = f2bf(xb.z); pb[3] = f2bf(xb.w);
            *(ushort4v*)&As[r * LDH + ch * 8] = pa;
            *(ushort4v*)&As[r * LDH + ch * 8 + 4] = pb;
            int4v vb = *(const int4v*)(WgT + (long)r * Ff + k0 + ch * 8);
            *(int4v*)&Bs[r * LDH + ch * 8] = vb;
        }
        __syncthreads();
        bf16x8 af[4], bfr[4];
        #pragma unroll
        for (int i = 0; i < 4; ++i)
            af[i] = *(const bf16x8*)&As[(wm + i * 16 + l16) * LDH + quad * 8];
        #pragma unroll
        for (int j = 0; j < 4; ++j)
            bfr[j] = *(const bf16x8*)&Bs[(wn + j * 16 + l16) * LDH + quad * 8];
        #pragma unroll
        for (int i = 0; i < 4; ++i)
            #pragma unroll
            for (int j = 0; j < 4; ++j)
                acc[i][j] = __builtin_amdgcn_mfma_f32_16x16x32_bf16(
                    af[i], bfr[j], acc[i][j], 0, 0, 0);
    }

    #pragma unroll
    for (int i = 0; i < 4; ++i) {
        int mb = m0 + wm + i * 16 + quad * 4;
        #pragma unroll
        for (int j = 0; j < 4; ++j) {
            int n = wn + j * 16 + l16;
            f32x4 v = acc[i][j];
            float bv = bg[n];
            unsigned short s0 = f2bf(v[0] + bv), s1 = f2bf(v[1] + bv);
            unsigned short s2 = f2bf(v[2] + bv), s3 = f2bf(v[3] + bv);
            h0b[(long)(mb + 0) * Ff + n] = s0;
            h0b[(long)(mb + 1) * Ff + n] = s1;
            h0b[(long)(mb + 2) * Ff + n] = s2;
            h0b[(long)(mb + 3) * Ff + n] = s3;
            ushort4v p; p[0] = s0; p[1] = s1; p[2] = s2; p[3] = s3;
            long ti = ((long)(mb >> 9) * Ff + n) * 512 + (mb & 511);
            *(ushort4v*)&h0T[ti] = p;
        }
    }
}

// ---------------- Gram -> Gaussian adjacency A via MFMA ----------------
// A[b,i,j] = (i==j) ? 0 : exp(-max(sq_i+sq_j-2*dot(h_i,h_j),0) / (2*sigma^2))
__global__ __launch_bounds__(256) void gram_A_mfma(
    const unsigned short* __restrict__ h0b, const float* __restrict__ sqv,
    const float* __restrict__ sigma, unsigned short* __restrict__ Aout)
{
    int b = blockIdx.z;
    const unsigned short* H = h0b + (long)b * Nn * Ff;
    const float* SQ = sqv + (long)b * Nn;
    unsigned short* Ab = Aout + (long)b * Nn * Nn;

    __shared__ unsigned short Is[128 * LDH];
    __shared__ unsigned short Js[128 * LDH];

    int tid = threadIdx.x;
    int lane = tid & 63;
    int wave = tid >> 6;
    int quad = lane >> 4, l16 = lane & 15;
    int wm = (wave >> 1) * 64, wn = (wave & 1) * 64;
    int i0 = blockIdx.x * 128, j0 = blockIdx.y * 128;

    f32x4 acc[4][4] = {};

    for (int k0 = 0; k0 < Ff; k0 += 32) {
        __syncthreads();
        #pragma unroll
        for (int l = 0; l < 2; ++l) {
            int idx = tid + l * 256;
            int r = idx >> 2, ch = idx & 3;
            int4v va = *(const int4v*)(H + (long)(i0 + r) * Ff + k0 + ch * 8);
            *(int4v*)&Is[r * LDH + ch * 8] = va;
            int4v vb = *(const int4v*)(H + (long)(j0 + r) * Ff + k0 + ch * 8);
            *(int4v*)&Js[r * LDH + ch * 8] = vb;
        }
        __syncthreads();
        bf16x8 af[4], bfr[4];
        #pragma unroll
        for (int i = 0; i < 4; ++i)
            af[i] = *(const bf16x8*)&Is[(wm + i * 16 + l16) * LDH + quad * 8];
        #pragma unroll
        for (int j = 0; j < 4; ++j)
            bfr[j] = *(const bf16x8*)&Js[(wn + j * 16 + l16) * LDH + quad * 8];
        #pragma unroll
        for (int i = 0; i < 4; ++i)
            #pragma unroll
            for (int j = 0; j < 4; ++j)
                acc[i][j] = __builtin_amdgcn_mfma_f32_16x16x32_bf16(
                    af[i], bfr[j], acc[i][j], 0, 0, 0);
    }

    float s = sigma[0];
    float inv2s2 = 1.0f / (2.0f * s * s);
    #pragma unroll
    for (int i = 0; i < 4; ++i) {
        int rb = i0 + wm + i * 16 + quad * 4;
        #pragma unroll
        for (int j = 0; j < 4; ++j) {
            int c = j0 + wn + j * 16 + l16;
            float sqc = SQ[c];
            f32x4 v = acc[i][j];
            #pragma unroll
            for (int r4 = 0; r4 < 4; ++r4) {
                int r = rb + r4;
                float d = fmaxf(SQ[r] + sqc - 2.0f * v[r4], 0.0f);
                unsigned short a = (r == c) ? (unsigned short)0
                                            : f2bf(__expf(-d * inv2s2));
                Ab[(long)r * Nn + c] = a;
            }
        }
    }
}

// ---------------- weight convert + transpose (fp32 -> bf16 transposed) ----------
__global__ __launch_bounds__(256) void convert_weights(
    const float* __restrict__ Wrel0, const float* __restrict__ Wroot0,
    const float* __restrict__ Wrel1, const float* __restrict__ Wroot1,
    const float* __restrict__ Wrel2, const float* __restrict__ Wroot2,
    const float* __restrict__ Wg,
    unsigned short* __restrict__ T0, unsigned short* __restrict__ T1,
    unsigned short* __restrict__ T2, unsigned short* __restrict__ T3,
    unsigned short* __restrict__ T4, unsigned short* __restrict__ T5,
    unsigned short* __restrict__ TG)
{
    int idx = blockIdx.x * 256 + threadIdx.x;   // total 344064
    if (idx >= 327680) {                         // WgT: [128 out][128 in]
        int e = idx - 327680;
        int o = e >> 7, i = e & 127;
        TG[e] = f2bf(Wg[(long)i * 128 + o]);
        return;
    }
    const float* src; unsigned short* dst; int kin; int e;
    if      (idx <  32768) { src = Wrel0;  dst = T0; kin = 128; e = idx; }
    else if (idx <  65536) { src = Wroot0; dst = T1; kin = 128; e = idx - 32768; }
    else if (idx < 131072) { src = Wrel1;  dst = T2; kin = 256; e = idx - 65536; }
    else if (idx < 196608) { src = Wroot1; dst = T3; kin = 256; e = idx - 131072; }
    else if (idx < 262144) { src = Wrel2;  dst = T4; kin = 256; e = idx - 196608; }
    else                   { src = Wroot2; dst = T5; kin = 256; e = idx - 262144; }
    int o = (kin == 128) ? (e >> 7) : (e >> 8);
    int i = e & (kin - 1);
    dst[e] = f2bf(src[(long)i * 256 + o]);      // conv out-dims are all 256
}

// ---------------- per-row sum of squares of h0b (bf16 in, fp32 out) --------------
__global__ __launch_bounds__(64) void rowsq_kernel(const unsigned short* __restrict__ h0b,
                                                   float* __restrict__ sq)
{
    int row = blockIdx.x;
    const unsigned short* r = h0b + (long)row * Ff;
    int lane = threadIdx.x;
    float a = bf2f(r[lane]), b = bf2f(r[lane + 64]);
    float v = a * a + b * b;
    #pragma unroll
    for (int off = 32; off; off >>= 1) v += __shfl_down(v, off);
    if (lane == 0) sq[row] = v;
}

// ---------------- mean pool over N (bf16 in, fp32 out) ----------------
__global__ __launch_bounds__(256) void pool_mean_kernel(const unsigned short* __restrict__ h3,
                                                        float* __restrict__ g)
{
    int b = blockIdx.x;
    int f = threadIdx.x;  // 256
    const unsigned short* p = h3 + (long)b * Nn * Hh + f;
    float s = 0.f;
    for (int n = 0; n < Nn; ++n) s += bf2f(p[n * Hh]);
    g[b * Hh + f] = s * (1.0f / (float)Nn);
}

// ---------------- g2 = relu(g @ W1 + b1) (fp32) ----------------
__global__ __launch_bounds__(256) void mlp1_kernel(const float* __restrict__ g,
                                                   const float* __restrict__ W1,
                                                   const float* __restrict__ b1,
                                                   float* __restrict__ g2)
{
    int b = blockIdx.x;
    int j = threadIdx.x;
    __shared__ float gs[Hh];
    gs[j] = g[b * Hh + j];
    __syncthreads();
    float s = b1[j];
    for (int k = 0; k < Hh; ++k) s += gs[k] * W1[k * Hh + j];
    g2[b * Hh + j] = fmaxf(s, 0.f);
}

// ---------------- out = g2 @ Wout + bout (fp32) ----------------
__global__ __launch_bounds__(64) void mlp_out_kernel(const float* __restrict__ g2,
                                                     const float* __restrict__ Wout,
                                                     const float* __restrict__ bout,
                                                     float* __restrict__ out)
{
    int b = blockIdx.x;
    int j = threadIdx.x;
    __shared__ float gs[Hh];
    for (int t = j; t < Hh; t += 64) gs[t] = g2[b * Hh + t];
    __syncthreads();
    if (j < OUTD) {
        float s = bout[j];
        for (int k = 0; k < Hh; ++k) s += gs[k] * Wout[k * OUTD + j];
        out[b * OUTD + j] = s;
    }
}

extern "C" void kernel_launch(void* const* d_in, const int* in_sizes, int n_in,
                              void* d_out, int out_size, void* d_ws, size_t ws_size,
                              hipStream_t stream) {
    const float* x      = (const float*)d_in[0];
    const float* sigma  = (const float*)d_in[4];
    const float* Wg     = (const float*)d_in[5];
    const float* bg     = (const float*)d_in[6];
    const float* Wrel0  = (const float*)d_in[7];
    const float* Wroot0 = (const float*)d_in[8];
    const float* brel0  = (const float*)d_in[9];
    const float* Wrel1  = (const float*)d_in[10];
    const float* Wroot1 = (const float*)d_in[11];
    const float* brel1  = (const float*)d_in[12];
    const float* Wrel2  = (const float*)d_in[13];
    const float* Wroot2 = (const float*)d_in[14];
    const float* brel2  = (const float*)d_in[15];
    const float* W1     = (const float*)d_in[16];
    const float* b1     = (const float*)d_in[17];
    const float* Wout   = (const float*)d_in[18];
    const float* bout   = (const float*)d_in[19];
    float* out = (float*)d_out;

    // Workspace layout (bytes)
    char* ws = (char*)d_ws;
    unsigned short* WgT  = (unsigned short*)(ws + 0);              // 32 KB
    unsigned short* h0b  = (unsigned short*)(ws + 16777216);       // 8 MB
    unsigned short* h0T  = (unsigned short*)(ws + 25165824);       // 8 MB
    float*          sq   = (float*)(ws + 33554432);                // 128 KB
    unsigned short* Aadj = (unsigned short*)(ws + 33685504);       // 32 MB
    unsigned short* agg  = (unsigned short*)(ws + 67239936);       // 16 MB
    unsigned short* h1b  = (unsigned short*)(ws + 84017152);       // 16 MB
    unsigned short* h1T  = (unsigned short*)(ws + 100794368);      // 16 MB
    unsigned short* h2b  = (unsigned short*)(ws + 117571584);      // 16 MB
    unsigned short* h2T  = (unsigned short*)(ws + 134348800);      // 16 MB
    unsigned short* h3b  = (unsigned short*)(ws + 151126016);      // 16 MB
    unsigned short* WrelT0  = (unsigned short*)(ws + 167903232);
    unsigned short* WrootT0 = (unsigned short*)(ws + 167968768);
    unsigned short* WrelT1  = (unsigned short*)(ws + 168034304);
    unsigned short* WrootT1 = (unsigned short*)(ws + 168165376);
    unsigned short* WrelT2  = (unsigned short*)(ws + 168296448);
    unsigned short* WrootT2 = (unsigned short*)(ws + 168427520);
    float*          g    = (float*)(ws + 168558592);
    float*          g2   = (float*)(ws + 168624128);

    // weights -> bf16 transposed (incl. WgT)
    convert_weights<<<1344, 256, 0, stream>>>(Wrel0, Wroot0, Wrel1, Wroot1, Wrel2, Wroot2, Wg,
                                              WrelT0, WrootT0, WrelT1, WrootT1, WrelT2, WrootT2,
                                              WgT);

    // h0 (bf16 MFMA), writes node-major + transposed
    h0_mfma<<<dim3(MTOT / 128, 1, 1), 256, 0, stream>>>(x, WgT, bg, h0b, h0T);

    // sq from bf16 h0 (consistent with MFMA Gram)
    rowsq_kernel<<<MTOT, 64, 0, stream>>>(h0b, sq);

    // A = exp(-dist/(2 sigma^2)), zero diag (MFMA Gram)
    gram_A_mfma<<<dim3(Nn / 128, Nn / 128, Bsz), 256, 0, stream>>>(h0b, sq, sigma, Aadj);

    // ---- layer 0 ----
    gemm_bf16<<<dim3(4, 1, Bsz), 256, 0, stream>>>(
        Aadj, h0T, nullptr, nullptr, nullptr, agg, nullptr,
        Nn, Ff, Nn, 0, Nn, 0,
        (long)Nn * Nn, (long)Ff * Nn, (long)Nn * Ff, 0);
    gemm_bf16<<<dim3(MTOT / 128, Hh / 128, 1), 256, 0, stream>>>(
        agg, WrelT0, h0b, WrootT0, brel0, h1b, h1T,
        MTOT, Hh, Ff, Ff, Ff, Ff, 0, 0, 0, 1);

    // ---- layer 1 ----
    gemm_bf16<<<dim3(4, 2, Bsz), 256, 0, stream>>>(
        Aadj, h1T, nullptr, nullptr, nullptr, agg, nullptr,
        Nn, Hh, Nn, 0, Nn, 0,
        (long)Nn * Nn, (long)Hh * Nn, (long)Nn * Hh, 0);
    gemm_bf16<<<dim3(MTOT / 128, Hh / 128, 1), 256, 0, stream>>>(
        agg, WrelT1, h1b, WrootT1, brel1, h2b, h2T,
        MTOT, Hh, Hh, Hh, Hh, Hh, 0, 0, 0, 1);

    // ---- layer 2 (no relu) ----
    gemm_bf16<<<dim3(4, 2, Bsz), 256, 0, stream>>>(
        Aadj, h2T, nullptr, nullptr, nullptr, agg, nullptr,
        Nn, Hh, Nn, 0, Nn, 0,
        (long)Nn * Nn, (long)Hh * Nn, (long)Nn * Hh, 0);
    gemm_bf16<<<dim3(MTOT / 128, Hh / 128, 1), 256, 0, stream>>>(
        agg, WrelT2, h2b, WrootT2, brel2, h3b, nullptr,
        MTOT, Hh, Hh, Hh, Hh, Hh, 0, 0, 0, 0);

    // pool + MLP head (fp32)
    pool_mean_kernel<<<Bsz, 256, 0, stream>>>(h3b, g);
    mlp1_kernel<<<Bsz, 256, 0, stream>>>(g, W1, b1, g2);
    mlp_out_kernel<<<Bsz, 64, 0, stream>>>(g2, Wout, bout, out);
}

// Round 4
// 288.905 us; speedup vs baseline: 3.0465x; 1.0615x over previous
//
#include <hip/hip_runtime.h>
#include <math.h>

// Problem constants
#define Bsz 64
#define Nn 512
#define Ff 128
#define Hh 256
#define OUTD 6
#define MTOT (Bsz * Nn)   // 32768

typedef __bf16 bf16x8 __attribute__((ext_vector_type(8)));
typedef float f32x4 __attribute__((ext_vector_type(4)));
typedef int int4v __attribute__((ext_vector_type(4)));
typedef unsigned short ushort4v __attribute__((ext_vector_type(4)));

__device__ __forceinline__ unsigned short f2bf(float f) {
    unsigned u = __float_as_uint(f);
    u += 0x7FFFu + ((u >> 16) & 1u);        // RNE
    return (unsigned short)(u >> 16);
}
__device__ __forceinline__ float bf2f(unsigned short s) {
    return __uint_as_float(((unsigned)s) << 16);
}

// XOR swizzle of the 16B k-chunk within a 64B LDS row (kills ds_read_b128 bank conflicts)
#define SWZ(r) (((r) ^ ((r) >> 2)) & 3)

// async 16B global->LDS (DMA; LDS dest = wave-uniform base + lane*16)
__device__ __forceinline__ void async_ld16(const unsigned short* g, unsigned short* l) {
    __builtin_amdgcn_global_load_lds(
        (const __attribute__((address_space(1))) void*)g,
        (__attribute__((address_space(3))) void*)l,
        16, 0, 0);
}

#define LDH 40   // padded LDS row stride (bf16) for the non-async h0 kernel

// ---------------- bf16 MFMA GEMM, optional fused second operand pair ----------------
// out = act( A0@B0 [+ A1@B1] + bias ); B operands TRANSPOSED (BT[n][k]); row stride == K.
// Batched via blockIdx.z strides. flags&1 = relu; flags&4 = column-sum pool into gpool
// (no C/CT store). CT (optional) = transposed copy [graph][n][node].
__global__ __launch_bounds__(256) void gemm_bf16(
    const unsigned short* __restrict__ A0, const unsigned short* __restrict__ B0T,
    const unsigned short* __restrict__ A1, const unsigned short* __restrict__ B1T,
    const float* __restrict__ bias,
    unsigned short* __restrict__ C, unsigned short* __restrict__ CT,
    float* __restrict__ gpool,
    int M, int Ntot, int K0, int K1,
    long strideA0, long strideB0, long strideC, int flags)
{
    int bz = blockIdx.z;
    A0 += (long)bz * strideA0;
    B0T += (long)bz * strideB0;
    if (C) C += (long)bz * strideC;

    __shared__ unsigned short As[128 * 32];   // 8 KB, 64B rows, swizzled chunks
    __shared__ unsigned short Bs[128 * 32];

    int tid = threadIdx.x;
    int lane = tid & 63;
    int wave = tid >> 6;
    int quad = lane >> 4, l16 = lane & 15;
    int wm = (wave >> 1) * 64, wn = (wave & 1) * 64;
    int m0 = blockIdx.x * 128, n0 = blockIdx.y * 128;

    int sr = lane >> 2;        // staging row within 16-row group
    int sc = lane & 3;         // staging chunk slot

    f32x4 acc[4][4] = {};

    #pragma unroll
    for (int pass = 0; pass < 2; ++pass) {
        const unsigned short* Ap = pass ? A1 : A0;
        const unsigned short* Bp = pass ? B1T : B0T;
        int K = pass ? K1 : K0;
        if (K == 0) continue;
        for (int k0 = 0; k0 < K; k0 += 32) {
            __syncthreads();
            #pragma unroll
            for (int t = 0; t < 2; ++t) {
                int r = wave * 32 + t * 16 + sr;
                int c = sc ^ SWZ(r);
                async_ld16(Ap + (long)(m0 + r) * K + k0 + c * 8,
                           As + (wave * 32 + t * 16) * 32);
                async_ld16(Bp + (long)(n0 + r) * K + k0 + c * 8,
                           Bs + (wave * 32 + t * 16) * 32);
            }
            __syncthreads();
            bf16x8 af[4], bfr[4];
            #pragma unroll
            for (int i = 0; i < 4; ++i) {
                int r = wm + i * 16 + l16;
                af[i] = *(const bf16x8*)&As[r * 32 + (quad ^ SWZ(r)) * 8];
            }
            #pragma unroll
            for (int j = 0; j < 4; ++j) {
                int r = wn + j * 16 + l16;
                bfr[j] = *(const bf16x8*)&Bs[r * 32 + (quad ^ SWZ(r)) * 8];
            }
            #pragma unroll
            for (int i = 0; i < 4; ++i)
                #pragma unroll
                for (int j = 0; j < 4; ++j)
                    acc[i][j] = __builtin_amdgcn_mfma_f32_16x16x32_bf16(
                        af[i], bfr[j], acc[i][j], 0, 0, 0);
        }
    }

    // ---- pooled epilogue (dense layer-2): column sums -> gpool ----
    if (flags & 4) {
        __syncthreads();                       // all frag reads done; reuse As
        float* fs = (float*)As;
        if (tid < 128) fs[tid] = 0.f;
        __syncthreads();
        #pragma unroll
        for (int j = 0; j < 4; ++j) {
            int nl = wn + j * 16 + l16;
            float bv = bias ? bias[n0 + nl] : 0.f;
            float cs = 16.f * bv;              // 16 rows in this lane's column slice
            #pragma unroll
            for (int i = 0; i < 4; ++i) {
                f32x4 v = acc[i][j];
                cs += v[0] + v[1] + v[2] + v[3];
            }
            atomicAdd(&fs[nl], cs);
        }
        __syncthreads();
        if (tid < 128)
            atomicAdd(&gpool[(long)(m0 >> 9) * Hh + n0 + tid], fs[tid]);
        return;
    }

    // ---- normal epilogue. C/D layout: col = lane&15, row = quad*4 + reg ----
    int ldc = Ntot;
    #pragma unroll
    for (int i = 0; i < 4; ++i) {
        int mb = m0 + wm + i * 16 + quad * 4;
        #pragma unroll
        for (int j = 0; j < 4; ++j) {
            int n = n0 + wn + j * 16 + l16;
            f32x4 v = acc[i][j];
            float bv = bias ? bias[n] : 0.0f;
            float o0 = v[0] + bv, o1 = v[1] + bv, o2 = v[2] + bv, o3 = v[3] + bv;
            if (flags & 1) {
                o0 = fmaxf(o0, 0.f); o1 = fmaxf(o1, 0.f);
                o2 = fmaxf(o2, 0.f); o3 = fmaxf(o3, 0.f);
            }
            unsigned short s0 = f2bf(o0), s1 = f2bf(o1), s2 = f2bf(o2), s3 = f2bf(o3);
            if (C) {
                C[(long)(mb + 0) * ldc + n] = s0;
                C[(long)(mb + 1) * ldc + n] = s1;
                C[(long)(mb + 2) * ldc + n] = s2;
                C[(long)(mb + 3) * ldc + n] = s3;
            }
            if (CT) {
                ushort4v p; p[0] = s0; p[1] = s1; p[2] = s2; p[3] = s3;
                long ti = ((long)(mb >> 9) * Ntot + n) * 512 + (mb & 511);
                *(ushort4v*)&CT[ti] = p;
            }
        }
    }
}

// ---------------- h0 = bf16(x) @ WgT + bg  (MFMA; writes h0b + h0T) ----------------
__global__ __launch_bounds__(256) void h0_mfma(
    const float* __restrict__ x, const unsigned short* __restrict__ WgT,
    const float* __restrict__ bg,
    unsigned short* __restrict__ h0b, unsigned short* __restrict__ h0T)
{
    __shared__ unsigned short As[128 * LDH];
    __shared__ unsigned short Bs[128 * LDH];

    int tid = threadIdx.x;
    int lane = tid & 63;
    int wave = tid >> 6;
    int quad = lane >> 4, l16 = lane & 15;
    int wm = (wave >> 1) * 64, wn = (wave & 1) * 64;
    int m0 = blockIdx.x * 128;          // N = 128 (single column block)

    f32x4 acc[4][4] = {};

    for (int k0 = 0; k0 < Ff; k0 += 32) {
        __syncthreads();
        #pragma unroll
        for (int l = 0; l < 2; ++l) {
            int idx = tid + l * 256;
            int r = idx >> 2, ch = idx & 3;
            const float* px = x + (long)(m0 + r) * Ff + k0 + ch * 8;
            float4 xa = *(const float4*)px;
            float4 xb = *(const float4*)(px + 4);
            ushort4v pa, pb;
            pa[0] = f2bf(xa.x); pa[1] = f2bf(xa.y); pa[2] = f2bf(xa.z); pa[3] = f2bf(xa.w);
            pb[0] = f2bf(xb.x); pb[1] = f2bf(xb.y); pb[2] = f2bf(xb.z); pb[3] = f2bf(xb.w);
            *(ushort4v*)&As[r * LDH + ch * 8] = pa;
            *(ushort4v*)&As[r * LDH + ch * 8 + 4] = pb;
            int4v vb = *(const int4v*)(WgT + (long)r * Ff + k0 + ch * 8);
            *(int4v*)&Bs[r * LDH + ch * 8] = vb;
        }
        __syncthreads();
        bf16x8 af[4], bfr[4];
        #pragma unroll
        for (int i = 0; i < 4; ++i)
            af[i] = *(const bf16x8*)&As[(wm + i * 16 + l16) * LDH + quad * 8];
        #pragma unroll
        for (int j = 0; j < 4; ++j)
            bfr[j] = *(const bf16x8*)&Bs[(wn + j * 16 + l16) * LDH + quad * 8];
        #pragma unroll
        for (int i = 0; i < 4; ++i)
            #pragma unroll
            for (int j = 0; j < 4; ++j)
                acc[i][j] = __builtin_amdgcn_mfma_f32_16x16x32_bf16(
                    af[i], bfr[j], acc[i][j], 0, 0, 0);
    }

    #pragma unroll
    for (int i = 0; i < 4; ++i) {
        int mb = m0 + wm + i * 16 + quad * 4;
        #pragma unroll
        for (int j = 0; j < 4; ++j) {
            int n = wn + j * 16 + l16;
            f32x4 v = acc[i][j];
            float bv = bg[n];
            unsigned short s0 = f2bf(v[0] + bv), s1 = f2bf(v[1] + bv);
            unsigned short s2 = f2bf(v[2] + bv), s3 = f2bf(v[3] + bv);
            h0b[(long)(mb + 0) * Ff + n] = s0;
            h0b[(long)(mb + 1) * Ff + n] = s1;
            h0b[(long)(mb + 2) * Ff + n] = s2;
            h0b[(long)(mb + 3) * Ff + n] = s3;
            ushort4v p; p[0] = s0; p[1] = s1; p[2] = s2; p[3] = s3;
            long ti = ((long)(mb >> 9) * Ff + n) * 512 + (mb & 511);
            *(ushort4v*)&h0T[ti] = p;
        }
    }
}

// ---------------- Gram -> Gaussian adjacency A via MFMA (async staging) ----------
__global__ __launch_bounds__(256) void gram_A_mfma(
    const unsigned short* __restrict__ h0b, const float* __restrict__ sqv,
    const float* __restrict__ sigma, unsigned short* __restrict__ Aout)
{
    int b = blockIdx.z;
    const unsigned short* H = h0b + (long)b * Nn * Ff;
    const float* SQ = sqv + (long)b * Nn;
    unsigned short* Ab = Aout + (long)b * Nn * Nn;

    __shared__ unsigned short Is[128 * 32];
    __shared__ unsigned short Js[128 * 32];

    int tid = threadIdx.x;
    int lane = tid & 63;
    int wave = tid >> 6;
    int quad = lane >> 4, l16 = lane & 15;
    int wm = (wave >> 1) * 64, wn = (wave & 1) * 64;
    int i0 = blockIdx.x * 128, j0 = blockIdx.y * 128;

    int sr = lane >> 2, sc = lane & 3;

    f32x4 acc[4][4] = {};

    for (int k0 = 0; k0 < Ff; k0 += 32) {
        __syncthreads();
        #pragma unroll
        for (int t = 0; t < 2; ++t) {
            int r = wave * 32 + t * 16 + sr;
            int c = sc ^ SWZ(r);
            async_ld16(H + (long)(i0 + r) * Ff + k0 + c * 8,
                       Is + (wave * 32 + t * 16) * 32);
            async_ld16(H + (long)(j0 + r) * Ff + k0 + c * 8,
                       Js + (wave * 32 + t * 16) * 32);
        }
        __syncthreads();
        bf16x8 af[4], bfr[4];
        #pragma unroll
        for (int i = 0; i < 4; ++i) {
            int r = wm + i * 16 + l16;
            af[i] = *(const bf16x8*)&Is[r * 32 + (quad ^ SWZ(r)) * 8];
        }
        #pragma unroll
        for (int j = 0; j < 4; ++j) {
            int r = wn + j * 16 + l16;
            bfr[j] = *(const bf16x8*)&Js[r * 32 + (quad ^ SWZ(r)) * 8];
        }
        #pragma unroll
        for (int i = 0; i < 4; ++i)
            #pragma unroll
            for (int j = 0; j < 4; ++j)
                acc[i][j] = __builtin_amdgcn_mfma_f32_16x16x32_bf16(
                    af[i], bfr[j], acc[i][j], 0, 0, 0);
    }

    float s = sigma[0];
    float inv2s2 = 1.0f / (2.0f * s * s);
    #pragma unroll
    for (int i = 0; i < 4; ++i) {
        int rb = i0 + wm + i * 16 + quad * 4;
        #pragma unroll
        for (int j = 0; j < 4; ++j) {
            int c = j0 + wn + j * 16 + l16;
            float sqc = SQ[c];
            f32x4 v = acc[i][j];
            #pragma unroll
            for (int r4 = 0; r4 < 4; ++r4) {
                int r = rb + r4;
                float d = fmaxf(SQ[r] + sqc - 2.0f * v[r4], 0.0f);
                unsigned short a = (r == c) ? (unsigned short)0
                                            : f2bf(__expf(-d * inv2s2));
                Ab[(long)r * Nn + c] = a;
            }
        }
    }
}

// ---------------- weight convert + transpose + gpool zero ----------
__global__ __launch_bounds__(256) void convert_weights(
    const float* __restrict__ Wrel0, const float* __restrict__ Wroot0,
    const float* __restrict__ Wrel1, const float* __restrict__ Wroot1,
    const float* __restrict__ Wrel2, const float* __restrict__ Wroot2,
    const float* __restrict__ Wg,
    unsigned short* __restrict__ T0, unsigned short* __restrict__ T1,
    unsigned short* __restrict__ T2, unsigned short* __restrict__ T3,
    unsigned short* __restrict__ T4, unsigned short* __restrict__ T5,
    unsigned short* __restrict__ TG, float* __restrict__ gpool)
{
    int idx = blockIdx.x * 256 + threadIdx.x;   // total 360448
    if (idx >= 344064) {                         // zero gpool [64*256]
        int e = idx - 344064;
        gpool[e] = 0.f;
        return;
    }
    if (idx >= 327680) {                         // WgT: [128 out][128 in]
        int e = idx - 327680;
        int o = e >> 7, i = e & 127;
        TG[e] = f2bf(Wg[(long)i * 128 + o]);
        return;
    }
    const float* src; unsigned short* dst; int kin; int e;
    if      (idx <  32768) { src = Wrel0;  dst = T0; kin = 128; e = idx; }
    else if (idx <  65536) { src = Wroot0; dst = T1; kin = 128; e = idx - 32768; }
    else if (idx < 131072) { src = Wrel1;  dst = T2; kin = 256; e = idx - 65536; }
    else if (idx < 196608) { src = Wroot1; dst = T3; kin = 256; e = idx - 131072; }
    else if (idx < 262144) { src = Wrel2;  dst = T4; kin = 256; e = idx - 196608; }
    else                   { src = Wroot2; dst = T5; kin = 256; e = idx - 262144; }
    int o = (kin == 128) ? (e >> 7) : (e >> 8);
    int i = e & (kin - 1);
    dst[e] = f2bf(src[(long)i * 256 + o]);      // conv out-dims are all 256
}

// ---------------- per-row sum of squares of h0b (bf16 in, fp32 out) --------------
__global__ __launch_bounds__(64) void rowsq_kernel(const unsigned short* __restrict__ h0b,
                                                   float* __restrict__ sq)
{
    int row = blockIdx.x;
    const unsigned short* r = h0b + (long)row * Ff;
    int lane = threadIdx.x;
    float a = bf2f(r[lane]), b = bf2f(r[lane + 64]);
    float v = a * a + b * b;
    #pragma unroll
    for (int off = 32; off; off >>= 1) v += __shfl_down(v, off);
    if (lane == 0) sq[row] = v;
}

// ---------------- head: mean + relu(g@W1+b1) @ Wout + bout ----------------
__global__ __launch_bounds__(256) void head_kernel(
    const float* __restrict__ gpool,
    const float* __restrict__ W1, const float* __restrict__ b1,
    const float* __restrict__ Wout, const float* __restrict__ bout,
    float* __restrict__ out)
{
    int b = blockIdx.x;
    int j = threadIdx.x;
    __shared__ float gs[Hh];
    __shared__ float g2[Hh];
    gs[j] = gpool[b * Hh + j] * (1.0f / (float)Nn);
    __syncthreads();
    float s = b1[j];
    for (int k = 0; k < Hh; ++k) s += gs[k] * W1[k * Hh + j];
    g2[j] = fmaxf(s, 0.f);
    __syncthreads();
    if (j < OUTD) {
        float s2 = bout[j];
        for (int k = 0; k < Hh; ++k) s2 += g2[k] * Wout[k * OUTD + j];
        out[b * OUTD + j] = s2;
    }
}

extern "C" void kernel_launch(void* const* d_in, const int* in_sizes, int n_in,
                              void* d_out, int out_size, void* d_ws, size_t ws_size,
                              hipStream_t stream) {
    const float* x      = (const float*)d_in[0];
    const float* sigma  = (const float*)d_in[4];
    const float* Wg     = (const float*)d_in[5];
    const float* bg     = (const float*)d_in[6];
    const float* Wrel0  = (const float*)d_in[7];
    const float* Wroot0 = (const float*)d_in[8];
    const float* brel0  = (const float*)d_in[9];
    const float* Wrel1  = (const float*)d_in[10];
    const float* Wroot1 = (const float*)d_in[11];
    const float* brel1  = (const float*)d_in[12];
    const float* Wrel2  = (const float*)d_in[13];
    const float* Wroot2 = (const float*)d_in[14];
    const float* brel2  = (const float*)d_in[15];
    const float* W1     = (const float*)d_in[16];
    const float* b1     = (const float*)d_in[17];
    const float* Wout   = (const float*)d_in[18];
    const float* bout   = (const float*)d_in[19];
    float* out = (float*)d_out;

    // Workspace layout (bytes)
    char* ws = (char*)d_ws;
    unsigned short* WgT  = (unsigned short*)(ws + 0);              // 32 KB
    unsigned short* h0b  = (unsigned short*)(ws + 16777216);       // 8 MB
    unsigned short* h0T  = (unsigned short*)(ws + 25165824);       // 8 MB
    float*          sq   = (float*)(ws + 33554432);                // 128 KB
    unsigned short* Aadj = (unsigned short*)(ws + 33685504);       // 32 MB
    unsigned short* agg  = (unsigned short*)(ws + 67239936);       // 16 MB
    unsigned short* h1b  = (unsigned short*)(ws + 84017152);       // 16 MB
    unsigned short* h1T  = (unsigned short*)(ws + 100794368);      // 16 MB
    unsigned short* h2b  = (unsigned short*)(ws + 117571584);      // 16 MB
    unsigned short* h2T  = (unsigned short*)(ws + 134348800);      // 16 MB
    unsigned short* WrelT0  = (unsigned short*)(ws + 167903232);
    unsigned short* WrootT0 = (unsigned short*)(ws + 167968768);
    unsigned short* WrelT1  = (unsigned short*)(ws + 168034304);
    unsigned short* WrootT1 = (unsigned short*)(ws + 168165376);
    unsigned short* WrelT2  = (unsigned short*)(ws + 168296448);
    unsigned short* WrootT2 = (unsigned short*)(ws + 168427520);
    float*          gpool = (float*)(ws + 168558592);              // 64 KB

    // weights -> bf16 transposed + gpool zero
    convert_weights<<<1408, 256, 0, stream>>>(Wrel0, Wroot0, Wrel1, Wroot1, Wrel2, Wroot2, Wg,
                                              WrelT0, WrootT0, WrelT1, WrootT1, WrelT2, WrootT2,
                                              WgT, gpool);

    // h0 (bf16 MFMA), writes node-major + transposed
    h0_mfma<<<dim3(MTOT / 128, 1, 1), 256, 0, stream>>>(x, WgT, bg, h0b, h0T);

    // sq from bf16 h0 (consistent with MFMA Gram)
    rowsq_kernel<<<MTOT, 64, 0, stream>>>(h0b, sq);

    // A = exp(-dist/(2 sigma^2)), zero diag (MFMA Gram)
    gram_A_mfma<<<dim3(Nn / 128, Nn / 128, Bsz), 256, 0, stream>>>(h0b, sq, sigma, Aadj);

    // ---- layer 0 ----
    gemm_bf16<<<dim3(4, 1, Bsz), 256, 0, stream>>>(
        Aadj, h0T, nullptr, nullptr, nullptr, agg, nullptr, nullptr,
        Nn, Ff, Nn, 0,
        (long)Nn * Nn, (long)Ff * Nn, (long)Nn * Ff, 0);
    gemm_bf16<<<dim3(MTOT / 128, Hh / 128, 1), 256, 0, stream>>>(
        agg, WrelT0, h0b, WrootT0, brel0, h1b, h1T, nullptr,
        MTOT, Hh, Ff, Ff, 0, 0, 0, 1);

    // ---- layer 1 ----
    gemm_bf16<<<dim3(4, 2, Bsz), 256, 0, stream>>>(
        Aadj, h1T, nullptr, nullptr, nullptr, agg, nullptr, nullptr,
        Nn, Hh, Nn, 0,
        (long)Nn * Nn, (long)Hh * Nn, (long)Nn * Hh, 0);
    gemm_bf16<<<dim3(MTOT / 128, Hh / 128, 1), 256, 0, stream>>>(
        agg, WrelT1, h1b, WrootT1, brel1, h2b, h2T, nullptr,
        MTOT, Hh, Hh, Hh, 0, 0, 0, 1);

    // ---- layer 2 (no relu; fused mean-pool, no h3 store) ----
    gemm_bf16<<<dim3(4, 2, Bsz), 256, 0, stream>>>(
        Aadj, h2T, nullptr, nullptr, nullptr, agg, nullptr, nullptr,
        Nn, Hh, Nn, 0,
        (long)Nn * Nn, (long)Hh * Nn, (long)Nn * Hh, 0);
    gemm_bf16<<<dim3(MTOT / 128, Hh / 128, 1), 256, 0, stream>>>(
        agg, WrelT2, h2b, WrootT2, brel2, nullptr, nullptr, gpool,
        MTOT, Hh, Hh, Hh, 0, 0, 0, 4);

    // head (mean + 2-layer MLP)
    head_kernel<<<Bsz, 256, 0, stream>>>(gpool, W1, b1, Wout, bout, out);
}

// Round 5
// 276.774 us; speedup vs baseline: 3.1801x; 1.0438x over previous
//
#include <hip/hip_runtime.h>
#include <math.h>

// Problem constants
#define Bsz 64
#define Nn 512
#define Ff 128
#define Hh 256
#define OUTD 6
#define MTOT (Bsz * Nn)   // 32768

typedef __bf16 bf16x8 __attribute__((ext_vector_type(8)));
typedef float f32x4 __attribute__((ext_vector_type(4)));
typedef int int4v __attribute__((ext_vector_type(4)));
typedef unsigned short ushort4v __attribute__((ext_vector_type(4)));

__device__ __forceinline__ unsigned short f2bf(float f) {
    unsigned u = __float_as_uint(f);
    u += 0x7FFFu + ((u >> 16) & 1u);        // RNE
    return (unsigned short)(u >> 16);
}
__device__ __forceinline__ float bf2f(unsigned short s) {
    return __uint_as_float(((unsigned)s) << 16);
}

// XOR swizzle of the 16B k-chunk within a 64B LDS row (kills ds_read_b128 bank conflicts)
#define SWZ(r) (((r) ^ ((r) >> 2)) & 3)

// async 16B global->LDS (DMA; LDS dest = wave-uniform base + lane*16)
__device__ __forceinline__ void async_ld16(const unsigned short* g, unsigned short* l) {
    __builtin_amdgcn_global_load_lds(
        (const __attribute__((address_space(1))) void*)g,
        (__attribute__((address_space(3))) void*)l,
        16, 0, 0);
}

#define LDH 40   // padded LDS row stride (bf16) for the non-async h0 kernel
#define TSZ (128 * 32)   // one LDS tile: 128 rows x 32 bf16 (8 KB)

// ---------------- bf16 MFMA GEMM, double-buffered, fused second operand pair -------
// out = act( A0@B0 [+ A1@B1] + bias ); B operands TRANSPOSED (BT[n][k]); row stride == K.
// Batched via blockIdx.z strides. flags&1 = relu; flags&4 = column-sum pool into gpool
// (no C/CT store). CT (optional) = transposed copy [graph][n][node].
__global__ __launch_bounds__(256) void gemm_bf16(
    const unsigned short* __restrict__ A0, const unsigned short* __restrict__ B0T,
    const unsigned short* __restrict__ A1, const unsigned short* __restrict__ B1T,
    const float* __restrict__ bias,
    unsigned short* __restrict__ C, unsigned short* __restrict__ CT,
    float* __restrict__ gpool,
    int M, int Ntot, int K0, int K1,
    long strideA0, long strideB0, long strideC, int flags)
{
    int bz = blockIdx.z;
    A0 += (long)bz * strideA0;
    B0T += (long)bz * strideB0;
    if (C) C += (long)bz * strideC;

    __shared__ unsigned short As[2 * TSZ];   // double-buffered, 64B rows, swizzled chunks
    __shared__ unsigned short Bs[2 * TSZ];

    int tid = threadIdx.x;
    int lane = tid & 63;
    int wave = tid >> 6;
    int quad = lane >> 4, l16 = lane & 15;
    int wm = (wave >> 1) * 64, wn = (wave & 1) * 64;
    int m0 = blockIdx.x * 128, n0 = blockIdx.y * 128;

    int sr = lane >> 2;        // staging row within 16-row group
    int sc = lane & 3;         // staging chunk slot

    int T0 = K0 >> 5, T1 = K1 >> 5;
    int T = T0 + T1;

    f32x4 acc[4][4] = {};

    // issue tile g's staging loads into buffer (g&1)
    auto issue = [&](int g) {
        const unsigned short* Ag; const unsigned short* Bg; int Kg, kk;
        if (g < T0) { Ag = A0; Bg = B0T; Kg = K0; kk = g << 5; }
        else        { Ag = A1; Bg = B1T; Kg = K1; kk = (g - T0) << 5; }
        unsigned short* Ad = As + (g & 1) * TSZ;
        unsigned short* Bd = Bs + (g & 1) * TSZ;
        #pragma unroll
        for (int t = 0; t < 2; ++t) {
            int r = wave * 32 + t * 16 + sr;
            int c = sc ^ SWZ(r);
            async_ld16(Ag + (long)(m0 + r) * Kg + kk + c * 8,
                       Ad + (wave * 32 + t * 16) * 32);
            async_ld16(Bg + (long)(n0 + r) * Kg + kk + c * 8,
                       Bd + (wave * 32 + t * 16) * 32);
        }
    };

    issue(0);
    for (int g = 0; g < T; ++g) {
        __syncthreads();                      // drains tile g's loads (issued last iter)
        if (g + 1 < T) issue(g + 1);          // overlaps with compute of tile g
        const unsigned short* Ab = As + (g & 1) * TSZ;
        const unsigned short* Bb = Bs + (g & 1) * TSZ;
        bf16x8 af[4], bfr[4];
        #pragma unroll
        for (int i = 0; i < 4; ++i) {
            int r = wm + i * 16 + l16;
            af[i] = *(const bf16x8*)&Ab[r * 32 + (quad ^ SWZ(r)) * 8];
        }
        #pragma unroll
        for (int j = 0; j < 4; ++j) {
            int r = wn + j * 16 + l16;
            bfr[j] = *(const bf16x8*)&Bb[r * 32 + (quad ^ SWZ(r)) * 8];
        }
        #pragma unroll
        for (int i = 0; i < 4; ++i)
            #pragma unroll
            for (int j = 0; j < 4; ++j)
                acc[i][j] = __builtin_amdgcn_mfma_f32_16x16x32_bf16(
                    af[i], bfr[j], acc[i][j], 0, 0, 0);
    }

    // ---- pooled epilogue (dense layer-2): column sums -> gpool ----
    if (flags & 4) {
        __syncthreads();                       // all frag reads done; reuse As
        float* fs = (float*)As;
        if (tid < 128) fs[tid] = 0.f;
        __syncthreads();
        #pragma unroll
        for (int j = 0; j < 4; ++j) {
            int nl = wn + j * 16 + l16;
            float bv = bias ? bias[n0 + nl] : 0.f;
            float cs = 16.f * bv;              // 16 rows in this lane's column slice
            #pragma unroll
            for (int i = 0; i < 4; ++i) {
                f32x4 v = acc[i][j];
                cs += v[0] + v[1] + v[2] + v[3];
            }
            atomicAdd(&fs[nl], cs);
        }
        __syncthreads();
        if (tid < 128)
            atomicAdd(&gpool[(long)(m0 >> 9) * Hh + n0 + tid], fs[tid]);
        return;
    }

    // ---- normal epilogue. C/D layout: col = lane&15, row = quad*4 + reg ----
    int ldc = Ntot;
    #pragma unroll
    for (int i = 0; i < 4; ++i) {
        int mb = m0 + wm + i * 16 + quad * 4;
        #pragma unroll
        for (int j = 0; j < 4; ++j) {
            int n = n0 + wn + j * 16 + l16;
            f32x4 v = acc[i][j];
            float bv = bias ? bias[n] : 0.0f;
            float o0 = v[0] + bv, o1 = v[1] + bv, o2 = v[2] + bv, o3 = v[3] + bv;
            if (flags & 1) {
                o0 = fmaxf(o0, 0.f); o1 = fmaxf(o1, 0.f);
                o2 = fmaxf(o2, 0.f); o3 = fmaxf(o3, 0.f);
            }
            unsigned short s0 = f2bf(o0), s1 = f2bf(o1), s2 = f2bf(o2), s3 = f2bf(o3);
            if (C) {
                C[(long)(mb + 0) * ldc + n] = s0;
                C[(long)(mb + 1) * ldc + n] = s1;
                C[(long)(mb + 2) * ldc + n] = s2;
                C[(long)(mb + 3) * ldc + n] = s3;
            }
            if (CT) {
                ushort4v p; p[0] = s0; p[1] = s1; p[2] = s2; p[3] = s3;
                long ti = ((long)(mb >> 9) * Ntot + n) * 512 + (mb & 511);
                *(ushort4v*)&CT[ti] = p;
            }
        }
    }
}

// ---------------- h0 = bf16(x) @ WgT + bg  (MFMA; writes h0b + h0T + sq) ------------
__global__ __launch_bounds__(256) void h0_mfma(
    const float* __restrict__ x, const unsigned short* __restrict__ WgT,
    const float* __restrict__ bg,
    unsigned short* __restrict__ h0b, unsigned short* __restrict__ h0T,
    float* __restrict__ sqv)
{
    __shared__ unsigned short As[128 * LDH];
    __shared__ unsigned short Bs[128 * LDH];
    __shared__ float rsq[128];

    int tid = threadIdx.x;
    int lane = tid & 63;
    int wave = tid >> 6;
    int quad = lane >> 4, l16 = lane & 15;
    int wm = (wave >> 1) * 64, wn = (wave & 1) * 64;
    int m0 = blockIdx.x * 128;          // N = 128 (single column block)

    f32x4 acc[4][4] = {};

    for (int k0 = 0; k0 < Ff; k0 += 32) {
        __syncthreads();
        #pragma unroll
        for (int l = 0; l < 2; ++l) {
            int idx = tid + l * 256;
            int r = idx >> 2, ch = idx & 3;
            const float* px = x + (long)(m0 + r) * Ff + k0 + ch * 8;
            float4 xa = *(const float4*)px;
            float4 xb = *(const float4*)(px + 4);
            ushort4v pa, pb;
            pa[0] = f2bf(xa.x); pa[1] = f2bf(xa.y); pa[2] = f2bf(xa.z); pa[3] = f2bf(xa.w);
            pb[0] = f2bf(xb.x); pb[1] = f2bf(xb.y); pb[2] = f2bf(xb.z); pb[3] = f2bf(xb.w);
            *(ushort4v*)&As[r * LDH + ch * 8] = pa;
            *(ushort4v*)&As[r * LDH + ch * 8 + 4] = pb;
            int4v vb = *(const int4v*)(WgT + (long)r * Ff + k0 + ch * 8);
            *(int4v*)&Bs[r * LDH + ch * 8] = vb;
        }
        __syncthreads();
        bf16x8 af[4], bfr[4];
        #pragma unroll
        for (int i = 0; i < 4; ++i)
            af[i] = *(const bf16x8*)&As[(wm + i * 16 + l16) * LDH + quad * 8];
        #pragma unroll
        for (int j = 0; j < 4; ++j)
            bfr[j] = *(const bf16x8*)&Bs[(wn + j * 16 + l16) * LDH + quad * 8];
        #pragma unroll
        for (int i = 0; i < 4; ++i)
            #pragma unroll
            for (int j = 0; j < 4; ++j)
                acc[i][j] = __builtin_amdgcn_mfma_f32_16x16x32_bf16(
                    af[i], bfr[j], acc[i][j], 0, 0, 0);
    }

    if (tid < 128) rsq[tid] = 0.f;
    __syncthreads();

    #pragma unroll
    for (int i = 0; i < 4; ++i) {
        int lrow = wm + i * 16 + quad * 4;   // local row of first of 4
        int mb = m0 + lrow;
        float rp0 = 0.f, rp1 = 0.f, rp2 = 0.f, rp3 = 0.f;
        #pragma unroll
        for (int j = 0; j < 4; ++j) {
            int n = wn + j * 16 + l16;
            f32x4 v = acc[i][j];
            float bv = bg[n];
            unsigned short s0 = f2bf(v[0] + bv), s1 = f2bf(v[1] + bv);
            unsigned short s2 = f2bf(v[2] + bv), s3 = f2bf(v[3] + bv);
            h0b[(long)(mb + 0) * Ff + n] = s0;
            h0b[(long)(mb + 1) * Ff + n] = s1;
            h0b[(long)(mb + 2) * Ff + n] = s2;
            h0b[(long)(mb + 3) * Ff + n] = s3;
            ushort4v p; p[0] = s0; p[1] = s1; p[2] = s2; p[3] = s3;
            long ti = ((long)(mb >> 9) * Ff + n) * 512 + (mb & 511);
            *(ushort4v*)&h0T[ti] = p;
            float f0 = bf2f(s0), f1 = bf2f(s1), f2 = bf2f(s2), f3 = bf2f(s3);
            rp0 += f0 * f0; rp1 += f1 * f1; rp2 += f2 * f2; rp3 += f3 * f3;
        }
        // reduce across the 16 lanes (same quad) covering these 4 rows
        #pragma unroll
        for (int m = 1; m < 16; m <<= 1) {
            rp0 += __shfl_xor(rp0, m);
            rp1 += __shfl_xor(rp1, m);
            rp2 += __shfl_xor(rp2, m);
            rp3 += __shfl_xor(rp3, m);
        }
        if (l16 == 0) {   // two waves share rows -> atomic
            atomicAdd(&rsq[lrow + 0], rp0);
            atomicAdd(&rsq[lrow + 1], rp1);
            atomicAdd(&rsq[lrow + 2], rp2);
            atomicAdd(&rsq[lrow + 3], rp3);
        }
    }
    __syncthreads();
    if (tid < 128) sqv[m0 + tid] = rsq[tid];
}

// ---------------- Gram -> Gaussian adjacency A via MFMA (dbuf async staging) -------
__global__ __launch_bounds__(256) void gram_A_mfma(
    const unsigned short* __restrict__ h0b, const float* __restrict__ sqv,
    const float* __restrict__ sigma, unsigned short* __restrict__ Aout)
{
    int b = blockIdx.z;
    const unsigned short* H = h0b + (long)b * Nn * Ff;
    const float* SQ = sqv + (long)b * Nn;
    unsigned short* Ab = Aout + (long)b * Nn * Nn;

    __shared__ unsigned short Is[2 * TSZ];
    __shared__ unsigned short Js[2 * TSZ];

    int tid = threadIdx.x;
    int lane = tid & 63;
    int wave = tid >> 6;
    int quad = lane >> 4, l16 = lane & 15;
    int wm = (wave >> 1) * 64, wn = (wave & 1) * 64;
    int i0 = blockIdx.x * 128, j0 = blockIdx.y * 128;

    int sr = lane >> 2, sc = lane & 3;

    f32x4 acc[4][4] = {};

    auto issue = [&](int g) {
        int kk = g << 5;
        unsigned short* Id = Is + (g & 1) * TSZ;
        unsigned short* Jd = Js + (g & 1) * TSZ;
        #pragma unroll
        for (int t = 0; t < 2; ++t) {
            int r = wave * 32 + t * 16 + sr;
            int c = sc ^ SWZ(r);
            async_ld16(H + (long)(i0 + r) * Ff + kk + c * 8,
                       Id + (wave * 32 + t * 16) * 32);
            async_ld16(H + (long)(j0 + r) * Ff + kk + c * 8,
                       Jd + (wave * 32 + t * 16) * 32);
        }
    };

    issue(0);
    for (int g = 0; g < (Ff >> 5); ++g) {
        __syncthreads();
        if (g + 1 < (Ff >> 5)) issue(g + 1);
        const unsigned short* Ib = Is + (g & 1) * TSZ;
        const unsigned short* Jb = Js + (g & 1) * TSZ;
        bf16x8 af[4], bfr[4];
        #pragma unroll
        for (int i = 0; i < 4; ++i) {
            int r = wm + i * 16 + l16;
            af[i] = *(const bf16x8*)&Ib[r * 32 + (quad ^ SWZ(r)) * 8];
        }
        #pragma unroll
        for (int j = 0; j < 4; ++j) {
            int r = wn + j * 16 + l16;
            bfr[j] = *(const bf16x8*)&Jb[r * 32 + (quad ^ SWZ(r)) * 8];
        }
        #pragma unroll
        for (int i = 0; i < 4; ++i)
            #pragma unroll
            for (int j = 0; j < 4; ++j)
                acc[i][j] = __builtin_amdgcn_mfma_f32_16x16x32_bf16(
                    af[i], bfr[j], acc[i][j], 0, 0, 0);
    }

    float s = sigma[0];
    float inv2s2 = 1.0f / (2.0f * s * s);
    #pragma unroll
    for (int i = 0; i < 4; ++i) {
        int rb = i0 + wm + i * 16 + quad * 4;
        #pragma unroll
        for (int j = 0; j < 4; ++j) {
            int c = j0 + wn + j * 16 + l16;
            float sqc = SQ[c];
            f32x4 v = acc[i][j];
            #pragma unroll
            for (int r4 = 0; r4 < 4; ++r4) {
                int r = rb + r4;
                float d = fmaxf(SQ[r] + sqc - 2.0f * v[r4], 0.0f);
                unsigned short a = (r == c) ? (unsigned short)0
                                            : f2bf(__expf(-d * inv2s2));
                Ab[(long)r * Nn + c] = a;
            }
        }
    }
}

// ---------------- weight convert + transpose + gpool zero ----------
__global__ __launch_bounds__(256) void convert_weights(
    const float* __restrict__ Wrel0, const float* __restrict__ Wroot0,
    const float* __restrict__ Wrel1, const float* __restrict__ Wroot1,
    const float* __restrict__ Wrel2, const float* __restrict__ Wroot2,
    const float* __restrict__ Wg,
    unsigned short* __restrict__ T0, unsigned short* __restrict__ T1,
    unsigned short* __restrict__ T2, unsigned short* __restrict__ T3,
    unsigned short* __restrict__ T4, unsigned short* __restrict__ T5,
    unsigned short* __restrict__ TG, float* __restrict__ gpool)
{
    int idx = blockIdx.x * 256 + threadIdx.x;   // total 360448
    if (idx >= 344064) {                         // zero gpool [64*256]
        int e = idx - 344064;
        gpool[e] = 0.f;
        return;
    }
    if (idx >= 327680) {                         // WgT: [128 out][128 in]
        int e = idx - 327680;
        int o = e >> 7, i = e & 127;
        TG[e] = f2bf(Wg[(long)i * 128 + o]);
        return;
    }
    const float* src; unsigned short* dst; int kin; int e;
    if      (idx <  32768) { src = Wrel0;  dst = T0; kin = 128; e = idx; }
    else if (idx <  65536) { src = Wroot0; dst = T1; kin = 128; e = idx - 32768; }
    else if (idx < 131072) { src = Wrel1;  dst = T2; kin = 256; e = idx - 65536; }
    else if (idx < 196608) { src = Wroot1; dst = T3; kin = 256; e = idx - 131072; }
    else if (idx < 262144) { src = Wrel2;  dst = T4; kin = 256; e = idx - 196608; }
    else                   { src = Wroot2; dst = T5; kin = 256; e = idx - 262144; }
    int o = (kin == 128) ? (e >> 7) : (e >> 8);
    int i = e & (kin - 1);
    dst[e] = f2bf(src[(long)i * 256 + o]);      // conv out-dims are all 256
}

// ---------------- head: mean + relu(g@W1+b1) @ Wout + bout ----------------
__global__ __launch_bounds__(256) void head_kernel(
    const float* __restrict__ gpool,
    const float* __restrict__ W1, const float* __restrict__ b1,
    const float* __restrict__ Wout, const float* __restrict__ bout,
    float* __restrict__ out)
{
    int b = blockIdx.x;
    int j = threadIdx.x;
    __shared__ float gs[Hh];
    __shared__ float g2[Hh];
    gs[j] = gpool[b * Hh + j] * (1.0f / (float)Nn);
    __syncthreads();
    float s = b1[j];
    for (int k = 0; k < Hh; ++k) s += gs[k] * W1[k * Hh + j];
    g2[j] = fmaxf(s, 0.f);
    __syncthreads();
    if (j < OUTD) {
        float s2 = bout[j];
        for (int k = 0; k < Hh; ++k) s2 += g2[k] * Wout[k * OUTD + j];
        out[b * OUTD + j] = s2;
    }
}

extern "C" void kernel_launch(void* const* d_in, const int* in_sizes, int n_in,
                              void* d_out, int out_size, void* d_ws, size_t ws_size,
                              hipStream_t stream) {
    const float* x      = (const float*)d_in[0];
    const float* sigma  = (const float*)d_in[4];
    const float* Wg     = (const float*)d_in[5];
    const float* bg     = (const float*)d_in[6];
    const float* Wrel0  = (const float*)d_in[7];
    const float* Wroot0 = (const float*)d_in[8];
    const float* brel0  = (const float*)d_in[9];
    const float* Wrel1  = (const float*)d_in[10];
    const float* Wroot1 = (const float*)d_in[11];
    const float* brel1  = (const float*)d_in[12];
    const float* Wrel2  = (const float*)d_in[13];
    const float* Wroot2 = (const float*)d_in[14];
    const float* brel2  = (const float*)d_in[15];
    const float* W1     = (const float*)d_in[16];
    const float* b1     = (const float*)d_in[17];
    const float* Wout   = (const float*)d_in[18];
    const float* bout   = (const float*)d_in[19];
    float* out = (float*)d_out;

    // Workspace layout (bytes)
    char* ws = (char*)d_ws;
    unsigned short* WgT  = (unsigned short*)(ws + 0);              // 32 KB
    unsigned short* h0b  = (unsigned short*)(ws + 16777216);       // 8 MB
    unsigned short* h0T  = (unsigned short*)(ws + 25165824);       // 8 MB
    float*          sq   = (float*)(ws + 33554432);                // 128 KB
    unsigned short* Aadj = (unsigned short*)(ws + 33685504);       // 32 MB
    unsigned short* agg  = (unsigned short*)(ws + 67239936);       // 16 MB
    unsigned short* h1b  = (unsigned short*)(ws + 84017152);       // 16 MB
    unsigned short* h1T  = (unsigned short*)(ws + 100794368);      // 16 MB
    unsigned short* h2b  = (unsigned short*)(ws + 117571584);      // 16 MB
    unsigned short* h2T  = (unsigned short*)(ws + 134348800);      // 16 MB
    unsigned short* WrelT0  = (unsigned short*)(ws + 167903232);
    unsigned short* WrootT0 = (unsigned short*)(ws + 167968768);
    unsigned short* WrelT1  = (unsigned short*)(ws + 168034304);
    unsigned short* WrootT1 = (unsigned short*)(ws + 168165376);
    unsigned short* WrelT2  = (unsigned short*)(ws + 168296448);
    unsigned short* WrootT2 = (unsigned short*)(ws + 168427520);
    float*          gpool = (float*)(ws + 168558592);              // 64 KB

    // weights -> bf16 transposed + gpool zero
    convert_weights<<<1408, 256, 0, stream>>>(Wrel0, Wroot0, Wrel1, Wroot1, Wrel2, Wroot2, Wg,
                                              WrelT0, WrootT0, WrelT1, WrootT1, WrelT2, WrootT2,
                                              WgT, gpool);

    // h0 (bf16 MFMA), writes node-major + transposed + row sumsq
    h0_mfma<<<dim3(MTOT / 128, 1, 1), 256, 0, stream>>>(x, WgT, bg, h0b, h0T, sq);

    // A = exp(-dist/(2 sigma^2)), zero diag (MFMA Gram, dbuf)
    gram_A_mfma<<<dim3(Nn / 128, Nn / 128, Bsz), 256, 0, stream>>>(h0b, sq, sigma, Aadj);

    // ---- layer 0 ----
    gemm_bf16<<<dim3(4, 1, Bsz), 256, 0, stream>>>(
        Aadj, h0T, nullptr, nullptr, nullptr, agg, nullptr, nullptr,
        Nn, Ff, Nn, 0,
        (long)Nn * Nn, (long)Ff * Nn, (long)Nn * Ff, 0);
    gemm_bf16<<<dim3(MTOT / 128, Hh / 128, 1), 256, 0, stream>>>(
        agg, WrelT0, h0b, WrootT0, brel0, h1b, h1T, nullptr,
        MTOT, Hh, Ff, Ff, 0, 0, 0, 1);

    // ---- layer 1 ----
    gemm_bf16<<<dim3(4, 2, Bsz), 256, 0, stream>>>(
        Aadj, h1T, nullptr, nullptr, nullptr, agg, nullptr, nullptr,
        Nn, Hh, Nn, 0,
        (long)Nn * Nn, (long)Hh * Nn, (long)Nn * Hh, 0);
    gemm_bf16<<<dim3(MTOT / 128, Hh / 128, 1), 256, 0, stream>>>(
        agg, WrelT1, h1b, WrootT1, brel1, h2b, h2T, nullptr,
        MTOT, Hh, Hh, Hh, 0, 0, 0, 1);

    // ---- layer 2 (no relu; fused mean-pool, no h3 store) ----
    gemm_bf16<<<dim3(4, 2, Bsz), 256, 0, stream>>>(
        Aadj, h2T, nullptr, nullptr, nullptr, agg, nullptr, nullptr,
        Nn, Hh, Nn, 0,
        (long)Nn * Nn, (long)Hh * Nn, (long)Nn * Hh, 0);
    gemm_bf16<<<dim3(MTOT / 128, Hh / 128, 1), 256, 0, stream>>>(
        agg, WrelT2, h2b, WrootT2, brel2, nullptr, nullptr, gpool,
        MTOT, Hh, Hh, Hh, 0, 0, 0, 4);

    // head (mean + 2-layer MLP)
    head_kernel<<<Bsz, 256, 0, stream>>>(gpool, W1, b1, Wout, bout, out);
}